// Round 16
// baseline (209.497 us; speedup 1.0000x reference)
//
#include <hip/hip_runtime.h>
#include <hip/hip_bf16.h>
#include <stdint.h>

// Sizes (fixed for this problem)
#define NHEADS 16
#define HDIM   64
#define DMODEL 1024
#define SEQ    2048
#define NB     2
#define MTOT   (NB*SEQ)     // 4096 rows of x
#define NTOT   (3*DMODEL)   // 3072 qkv cols
#define KTOT   DMODEL       // 1024

// fold (1/8)*log2(e) into Q so softmax runs in exp2 domain
#define QSCALE 0.18033688011112042f

typedef __attribute__((ext_vector_type(8)))  short          bf16x8;
typedef __attribute__((ext_vector_type(4)))  float          f32x4;
typedef __attribute__((ext_vector_type(8)))  unsigned short u16x8;

__device__ __forceinline__ unsigned short f2bf(float f) {
  unsigned u = __builtin_bit_cast(unsigned, f);
  u += 0x7fffu + ((u >> 16) & 1u);          // round-to-nearest-even
  return (unsigned short)(u >> 16);
}

__device__ __forceinline__ f32x4 vmax4(f32x4 a, f32x4 b) {
  f32x4 r;
  r[0]=fmaxf(a[0],b[0]); r[1]=fmaxf(a[1],b[1]);
  r[2]=fmaxf(a[2],b[2]); r[3]=fmaxf(a[3],b[3]);
  return r;
}

__device__ __forceinline__ void async_copy16(void* lds, const void* g) {
  __builtin_amdgcn_global_load_lds(
      (const __attribute__((address_space(1))) unsigned int*)g,
      (__attribute__((address_space(3))) unsigned int*)lds, 16, 0, 0);
}

// ---------------------------------------------------------------- convert x
__global__ void convert_x_kernel(const float* __restrict__ x,
                                 unsigned short* __restrict__ xb) {
  int i = blockIdx.x * 256 + threadIdx.x;
  const f32x4* xv = reinterpret_cast<const f32x4*>(x);
  f32x4 a = xv[2*i];
  f32x4 b = xv[2*i + 1];
  u16x8 r;
  r[0]=f2bf(a[0]); r[1]=f2bf(a[1]); r[2]=f2bf(a[2]); r[3]=f2bf(a[3]);
  r[4]=f2bf(b[0]); r[5]=f2bf(b[1]); r[6]=f2bf(b[2]); r[7]=f2bf(b[3]);
  reinterpret_cast<u16x8*>(xb)[i] = r;
}

// --------------------------------------- transpose + permute + convert W
__global__ void transpose_w_kernel(const float* __restrict__ W,
                                   unsigned short* __restrict__ Wt) {
  __shared__ float tile[64][65];
  int j0 = blockIdx.x * 64;
  int k0 = blockIdx.y * 64;
  int tid = threadIdx.x;
  int lr = tid >> 6;
  int lc = tid & 63;
  #pragma unroll
  for (int i = 0; i < 16; ++i) {
    int r = i*4 + lr;
    tile[r][lc] = W[(size_t)(k0 + r)*NTOT + j0 + lc];
  }
  __syncthreads();
  #pragma unroll
  for (int i = 0; i < 16; ++i) {
    int jr = i*4 + lr;
    int j  = j0 + jr;
    int oc = (j % 3)*DMODEL + (j / 3);
    Wt[(size_t)oc*KTOT + k0 + lc] = f2bf(tile[lc][jr]);
  }
}

// ---------------------------------------------------------------- QKV GEMM
// R11 structure (kept): A+B double-buffered at BK=32, one barrier/iter,
// T2 swizzle (seg ^ ((row>>1)&3)); V-epilogue LDS transpose.
#define BM 128
#define BN 128
#define BK2 32
#define NBX (NTOT/BN)    // 24
#define NBY (MTOT/BM)    // 32
#define EPSTRIDE 136     // epilogue LDS row stride (elems): b64/b128 aligned
__launch_bounds__(256)
__global__ void qkv_gemm_kernel(const unsigned short* __restrict__ xb,
                                const unsigned short* __restrict__ wt,
                                const float* __restrict__ bqkv,
                                unsigned short* __restrict__ Qb,
                                unsigned short* __restrict__ Kb,
                                unsigned short* __restrict__ Vt) {
  __shared__ __align__(16) unsigned char gsm[128*EPSTRIDE*2]; // 34816 B
  unsigned short* As = (unsigned short*)gsm;            // [2][128*32] 16 KB
  unsigned short* Bs = (unsigned short*)(gsm + 16384);  // [2][128*32] 16 KB
  unsigned short* Ep = (unsigned short*)gsm;            // epilogue transpose

  int tid = threadIdx.x;
  int w = tid >> 6, l = tid & 63;
  int m0 = blockIdx.y * BM;
  int n0 = blockIdx.x * BN;
  int ln = l & 15, lg = l >> 4;
  int wm = (w >> 1) * 64;
  int wn = (w & 1) * 64;

  f32x4 acc[4][4];
  const f32x4 zero4 = {0.f, 0.f, 0.f, 0.f};
  #pragma unroll
  for (int i = 0; i < 4; ++i)
    #pragma unroll
    for (int j = 0; j < 4; ++j) acc[i][j] = zero4;

  // stage: linear LDS dest (wave-uniform base + lane*16B), pre-swizzled src
  #define STAGE2(BUF, KT)                                                     \
  do {                                                                        \
    _Pragma("unroll")                                                         \
    for (int i = 0; i < 2; ++i) {                                             \
      int row  = i*64 + w*16 + (l >> 2);                                      \
      int seg  = (l & 3) ^ ((row >> 1) & 3);                                  \
      async_copy16(gsm + (BUF)*8192 + i*4096 + w*1024,                        \
                   &xb[(size_t)(m0 + row)*KTOT + (KT)*BK2 + seg*8]);          \
      async_copy16(gsm + 16384 + (BUF)*8192 + i*4096 + w*1024,                \
                   &wt[(size_t)(n0 + row)*KTOT + (KT)*BK2 + seg*8]);          \
    }                                                                         \
  } while (0)

  STAGE2(0, 0);
  asm volatile("s_waitcnt vmcnt(0)" ::: "memory");
  __syncthreads();

  for (int kt = 0; kt < KTOT/BK2; ++kt) {
    int cur = kt & 1;
    if (kt < KTOT/BK2 - 1) STAGE2(cur ^ 1, kt + 1);   // covered by compute

    bf16x8 af[4], bfr[4];
    #pragma unroll
    for (int mi = 0; mi < 4; ++mi) {
      int ra = wm + mi*16 + ln;
      af[mi] = *reinterpret_cast<const bf16x8*>(
          &As[cur*4096 + ra*BK2 + ((lg ^ ((ra >> 1) & 3)) << 3)]);
    }
    #pragma unroll
    for (int ni = 0; ni < 4; ++ni) {
      int rb = wn + ni*16 + ln;
      bfr[ni] = *reinterpret_cast<const bf16x8*>(
          &Bs[cur*4096 + rb*BK2 + ((lg ^ ((rb >> 1) & 3)) << 3)]);
    }
    #pragma unroll
    for (int mi = 0; mi < 4; ++mi)
      #pragma unroll
      for (int ni = 0; ni < 4; ++ni)
        acc[mi][ni] = __builtin_amdgcn_mfma_f32_16x16x32_bf16(af[mi], bfr[ni], acc[mi][ni], 0, 0, 0);

    __syncthreads();   // drains prefetch (implicit vmcnt0) + LDS reads
  }
  #undef STAGE2

  int r4 = lg * 4;
  if (n0 >= 2*DMODEL) {
    // ---- V block (uniform c==2): LDS transpose -> coalesced Vt stores
    int hd0 = n0 - 2*DMODEL;
    #pragma unroll
    for (int mi = 0; mi < 4; ++mi) {
      #pragma unroll
      for (int ni = 0; ni < 4; ++ni) {
        int col = wn + ni*16 + ln;                 // hd_local
        float bias = bqkv[(hd0 + col)*3 + 2];
        int rb = wm + mi*16 + r4;                  // t_local base (mult of 4)
        ushort4 pk4;
        pk4.x = f2bf(acc[mi][ni][0] + bias);
        pk4.y = f2bf(acc[mi][ni][1] + bias);
        pk4.z = f2bf(acc[mi][ni][2] + bias);
        pk4.w = f2bf(acc[mi][ni][3] + bias);
        *reinterpret_cast<ushort4*>(&Ep[col*EPSTRIDE + rb]) = pk4;
      }
    }
    __syncthreads();
    int n = m0 >> 11, t0 = m0 & 2047;
    #pragma unroll
    for (int pass = 0; pass < 8; ++pass) {
      int hdl = pass*16 + (tid >> 4);
      int seg = tid & 15;
      bf16x8 v = *reinterpret_cast<const bf16x8*>(&Ep[hdl*EPSTRIDE + seg*8]);
      int hd = hd0 + hdl, h = hd >> 6, d = hd & 63;
      *reinterpret_cast<bf16x8*>(
          &Vt[(((size_t)(n*NHEADS + h)*HDIM + d) << 11) + t0 + seg*8]) = v;
    }
  } else {
    // ---- Q/K blocks (c==0/1): 32B-contiguous per 16-lane group
    #pragma unroll
    for (int mi = 0; mi < 4; ++mi) {
      #pragma unroll
      for (int ni = 0; ni < 4; ++ni) {
        int nc = n0 + wn + ni*16 + ln;
        int c  = nc >> 10;
        int hd = nc & 1023;
        int h = hd >> 6, d = hd & 63;
        float bias = bqkv[hd*3 + c];
        float qs = (c == 0) ? QSCALE : 1.0f;   // fold softmax scale into Q
        #pragma unroll
        for (int j = 0; j < 4; ++j) {
          int m = m0 + wm + mi*16 + r4 + j;
          int n = m >> 11, t = m & 2047;
          unsigned short val = f2bf((acc[mi][ni][j] + bias) * qs);
          size_t nh = (size_t)(n*NHEADS + h);
          if (c == 0) Qb[((nh*SEQ + t) << 6) + d] = val;
          else        Kb[((nh*SEQ + t) << 6) + d] = val;
        }
      }
    }
  }
}

// ---------------------------------------------------------------- attention
// R16: V OFF the LDS pipe. Pipe audit showed LDS-BW-bound (22KB/wave-tile
// ~= 92% LDS busy = the 30% "idle"). V is L2-resident -> read direct from
// global into regs (issued at iteration top, consumed by PV ~600cy later
// under QKT+softmax cover). K stays LDS-staged (3-buffer). LDS traffic
// 22KB -> 13KB per wave-tile. R15 skeleton otherwise unchanged (T15
// S-double-pipeline, defer-max, cvt_pk, final aliasing barrier).
#define PROW    88                  // P row stride, bf16 elems (176 B)
#define POFF    24576               // P regions start (after 3 K bufs)
#define PBYTES  2816                // 16 rows x 176 B per wave
#define OREGION 4352                // epilogue obuf: 16 x 68 f32 (reuses LDS)
__launch_bounds__(512)
__global__ void attn_kernel(const unsigned short* __restrict__ Qb,
                            const unsigned short* __restrict__ Kb,
                            const unsigned short* __restrict__ Vt,
                            float* __restrict__ out) {
  __shared__ __align__(16) unsigned char smem[POFF + 8*PBYTES]; // 47104 B
  int tid = threadIdx.x;
  int w = tid >> 6, l = tid & 63;
  int ln = l & 15, lg = l >> 4;

  unsigned short* Pw  = (unsigned short*)(smem + POFF + w * PBYTES);
  float*          obw = (float*)         (smem + w * OREGION); // post-loop only

  // XCD clustering: 512 blocks, 8 XCDs -> each XCD owns 4 heads
  int fid  = blockIdx.x;
  int xcd  = fid & 7, idx = fid >> 3;       // idx 0..63
  int bh   = xcd * 4 + (idx >> 4);          // 0..31
  int qblk = idx & 15;                      // 0..15 (128 q-rows each)
  int q0   = qblk * 128 + w * 16;

  const unsigned short* Qh = Qb + (size_t)bh * SEQ * HDIM;
  const unsigned short* Kh = Kb + (size_t)bh * SEQ * HDIM;
  const unsigned short* Vh = Vt + (size_t)bh * HDIM * SEQ;

  // staging mapping: 512 threads cover one 64x64 bf16 K tile in ONE call
  int srow = w*8 + (l >> 3);      // row 0..63
  int sseg = (l & 7) ^ (srow & 7);// inverse-swizzled 16B segment

  // Q B-fragments (col = q = ln), d-windows dw=0,1
  bf16x8 qf[2];
  #pragma unroll
  for (int dw = 0; dw < 2; ++dw)
    qf[dw] = *reinterpret_cast<const bf16x8*>(&Qh[(size_t)(q0 + ln)*HDIM + dw*32 + lg*8]);

  // per-lane V row bases (loop-invariant): V[d=db*16+ln][*]
  const unsigned short* vrow0 = Vh + (size_t)(0*16 + ln)*SEQ + lg*8;
  const unsigned short* vrow1 = Vh + (size_t)(1*16 + ln)*SEQ + lg*8;
  const unsigned short* vrow2 = Vh + (size_t)(2*16 + ln)*SEQ + lg*8;
  const unsigned short* vrow3 = Vh + (size_t)(3*16 + ln)*SEQ + lg*8;

  const f32x4 zero4 = {0.f, 0.f, 0.f, 0.f};
  f32x4 o[4];
  #pragma unroll
  for (int db = 0; db < 4; ++db) o[db] = zero4;
  f32x4 psum4 = zero4;
  float mrow = -INFINITY;
  f32x4 sA[4], sB[4];
  bf16x8 vf[2][4];   // V fragments for the tile consumed by SMPV this iter

  int xorE = (ln & 7) << 3;        // element-index XOR for swizzled ds_read
  int coff0 = (((     lg*8) ^ xorE)) * 2;   // d-window 0 column bytes
  int coff1 = (((32 + lg*8) ^ xorE)) * 2;   // d-window 1 column bytes
  int rbyte = ln * 128;                     // fragment row base bytes
  const unsigned char* kv0 = smem + rbyte + coff0;
  const unsigned char* kv1 = smem + rbyte + coff1;

  // STAGE one 64-key K tile into buffer BUF
  #define STAGE(BUF, KEY0)                                                    \
  do {                                                                        \
    async_copy16(smem + (BUF)*8192 + w*1024,                                  \
                 &Kh[(size_t)((KEY0) + srow)*HDIM + sseg*8]);                 \
  } while (0)

  // issue V loads (global -> regs) for tile with first key KEY0
  #define LOADV(KEY0)                                                         \
  do {                                                                        \
    _Pragma("unroll")                                                         \
    for (int kw = 0; kw < 2; ++kw) {                                          \
      vf[kw][0] = *reinterpret_cast<const bf16x8*>(vrow0 + (KEY0) + kw*32);   \
      vf[kw][1] = *reinterpret_cast<const bf16x8*>(vrow1 + (KEY0) + kw*32);   \
      vf[kw][2] = *reinterpret_cast<const bf16x8*>(vrow2 + (KEY0) + kw*32);   \
      vf[kw][3] = *reinterpret_cast<const bf16x8*>(vrow3 + (KEY0) + kw*32);   \
    }                                                                         \
  } while (0)

  // QK^T for tile in K-buffer CUR -> SCUR (pure MFMA + ds_read stream)
  #define QKT(CUR, SCUR)                                                      \
  do {                                                                        \
    _Pragma("unroll")                                                         \
    for (int kb = 0; kb < 4; ++kb) {                                          \
      bf16x8 k0 = *reinterpret_cast<const bf16x8*>(kv0 + (CUR)*8192 + kb*2048);\
      bf16x8 k1 = *reinterpret_cast<const bf16x8*>(kv1 + (CUR)*8192 + kb*2048);\
      f32x4 t0 = __builtin_amdgcn_mfma_f32_16x16x32_bf16(k0, qf[0], zero4, 0, 0, 0);\
      SCUR[kb] = __builtin_amdgcn_mfma_f32_16x16x32_bf16(k1, qf[1], t0,    0, 0, 0);\
    }                                                                         \
  } while (0)

  // softmax on SPREV + PV with V fragments in regs (vf)
  #define SMPV(SPREV)                                                         \
  do {                                                                        \
    f32x4 m4 = vmax4(vmax4(SPREV[0], SPREV[1]), vmax4(SPREV[2], SPREV[3]));   \
    float localmax = fmaxf(fmaxf(fmaxf(m4[0], m4[1]), m4[2]), m4[3]);         \
    if (!__all(localmax <= mrow + 8.f)) {                                     \
      float pm = localmax;                                                    \
      pm = fmaxf(pm, __shfl_xor(pm, 16));                                     \
      pm = fmaxf(pm, __shfl_xor(pm, 32));                                     \
      float mn  = fmaxf(mrow, pm);                                            \
      float scl = __builtin_amdgcn_exp2f(mrow - mn);                          \
      mrow = mn;                                                              \
      psum4 *= scl;                                                           \
      _Pragma("unroll")                                                       \
      for (int db = 0; db < 4; ++db)                                          \
        _Pragma("unroll")                                                     \
        for (int r = 0; r < 4; ++r) o[db][r] *= scl;                          \
    }                                                                         \
    _Pragma("unroll")                                                         \
    for (int kb = 0; kb < 4; ++kb) {                                          \
      _Pragma("unroll")                                                       \
      for (int r = 0; r < 4; ++r)                                             \
        SPREV[kb][r] = __builtin_amdgcn_exp2f(SPREV[kb][r] - mrow);           \
      psum4 += SPREV[kb];                                                     \
    }                                                                         \
    _Pragma("unroll")                                                         \
    for (int kb = 0; kb < 4; ++kb) {                                          \
      uint2 pk;                                                               \
      asm("v_cvt_pk_bf16_f32 %0, %1, %2" : "=v"(pk.x) : "v"(SPREV[kb][0]), "v"(SPREV[kb][1]));\
      asm("v_cvt_pk_bf16_f32 %0, %1, %2" : "=v"(pk.y) : "v"(SPREV[kb][2]), "v"(SPREV[kb][3]));\
      *reinterpret_cast<uint2*>(&Pw[ln*PROW + kb*16 + 4*lg]) = pk;            \
    }                                                                         \
    _Pragma("unroll")                                                         \
    for (int kw = 0; kw < 2; ++kw) {                                          \
      bf16x8 pb = *reinterpret_cast<const bf16x8*>(&Pw[ln*PROW + kw*32 + lg*8]);\
      __builtin_amdgcn_s_setprio(1);                                          \
      _Pragma("unroll")                                                       \
      for (int db = 0; db < 4; ++db)                                          \
        o[db] = __builtin_amdgcn_mfma_f32_16x16x32_bf16(vf[kw][db], pb, o[db], 0, 0, 0);\
      __builtin_amdgcn_s_setprio(0);                                          \
    }                                                                         \
  } while (0)

  #define ENDTILE                                                             \
  do {                                                                        \
    asm volatile("s_waitcnt vmcnt(0)" ::: "memory");                          \
    __builtin_amdgcn_s_barrier();                                             \
    asm volatile("" ::: "memory");                                            \
  } while (0)

  // FULL iteration t: stage K(t+1), load V(t-1), QK(t)->SCUR, SM+PV(t-1)
  #define FULL(KV, CUR, NXT, SPREV, SCUR)                                     \
  do {                                                                        \
    STAGE(NXT, ((KV) + 1) * 64);                                              \
    LOADV(((KV) - 1) * 64);                                                   \
    QKT(CUR, SCUR);                                                           \
    SMPV(SPREV);                                                              \
    ENDTILE;                                                                  \
  } while (0)

  // ---- prologue: K(0) staged+QK'd, K(1) staged
  STAGE(0, 0);
  ENDTILE;                 // K buffer 0 ready
  STAGE(1, 64);
  QKT(0, sA);              // S(0) -> sA
  ENDTILE;                 // K buffer 1 ready

  // ---- main loop t = 1..30 (6-unrolled: buffer period 3 x S period 2)
  for (int t = 1; t < 31; t += 6) {
    FULL(t + 0, 1, 2, sA, sB);
    FULL(t + 1, 2, 0, sB, sA);
    FULL(t + 2, 0, 1, sA, sB);
    FULL(t + 3, 1, 2, sB, sA);
    FULL(t + 4, 2, 0, sA, sB);
    FULL(t + 5, 0, 1, sB, sA);
  }

  // ---- t = 31: no stage; V(30) loads, QK(31)->sB (K buf 1), SM+PV(30)
  LOADV(30 * 64);
  QKT(1, sB);
  SMPV(sA);
  ENDTILE;
  // ---- final: V(31) loads, SM+PV(31)
  LOADV(31 * 64);
  SMPV(sB);

  // obw aliases K-staging + P LDS — all waves must finish P reads first.
  __syncthreads();

  #undef FULL
  #undef ENDTILE
  #undef SMPV
  #undef QKT
  #undef LOADV
  #undef STAGE

  // ---- post-loop: row-sum reduce (once), normalize, transpose, store
  float ls = (psum4[0] + psum4[1]) + (psum4[2] + psum4[3]);
  ls += __shfl_xor(ls, 16);
  ls += __shfl_xor(ls, 32);
  float inv = 1.f / ls;

  #pragma unroll
  for (int db = 0; db < 4; ++db)
    #pragma unroll
    for (int r = 0; r < 4; ++r)
      obw[ln*68 + db*16 + 4*lg + r] = o[db][r] * inv;
  asm volatile("s_waitcnt lgkmcnt(0)" ::: "memory");
  int n = bh >> 4, h = bh & 15;
  #pragma unroll
  for (int p = 0; p < 4; ++p) {
    int q = p*4 + lg;
    f32x4 vv = *reinterpret_cast<const f32x4*>(&obw[q*68 + ln*4]);
    *reinterpret_cast<f32x4*>(
        &out[((size_t)(n*SEQ + q0 + q))*DMODEL + h*HDIM + ln*4]) = vv;
  }
}

// ---------------------------------------------------------------- launcher
extern "C" void kernel_launch(void* const* d_in, const int* in_sizes, int n_in,
                              void* d_out, int out_size, void* d_ws, size_t ws_size,
                              hipStream_t stream) {
  const float* x    = (const float*)d_in[0];
  // d_in[1] = mask: constant shift along query axis inside softmax -> no-op
  const float* Wq   = (const float*)d_in[2];
  const float* bq   = (const float*)d_in[3];
  float* out = (float*)d_out;

  unsigned short* xb = (unsigned short*)d_ws;                    // [4096][1024]
  unsigned short* wt = xb + (size_t)MTOT*KTOT;                   // [3072][1024]
  unsigned short* Qb = wt + (size_t)NTOT*KTOT;                   // [32][2048][64]
  unsigned short* Kb = Qb + (size_t)NB*NHEADS*SEQ*HDIM;          // [32][2048][64]
  unsigned short* Vt = Kb + (size_t)NB*NHEADS*SEQ*HDIM;          // [32][64][2048]

  convert_x_kernel<<<(MTOT*KTOT/8)/256, 256, 0, stream>>>(x, xb);
  transpose_w_kernel<<<dim3(NTOT/64, KTOT/64), 256, 0, stream>>>(Wq, wt);
  qkv_gemm_kernel<<<dim3(NBX, NBY), 256, 0, stream>>>(xb, wt, bq, Qb, Kb, Vt);
  attn_kernel<<<512, 512, 0, stream>>>(Qb, Kb, Vt, out);
}

// Round 17
// 115.940 us; speedup vs baseline: 1.8070x; 1.8070x over previous
//
#include <hip/hip_runtime.h>
#include <hip/hip_bf16.h>
#include <stdint.h>

// Sizes (fixed for this problem)
#define NHEADS 16
#define HDIM   64
#define DMODEL 1024
#define SEQ    2048
#define NB     2
#define MTOT   (NB*SEQ)     // 4096 rows of x
#define NTOT   (3*DMODEL)   // 3072 qkv cols
#define KTOT   DMODEL       // 1024

// fold (1/8)*log2(e) into Q so softmax runs in exp2 domain
#define QSCALE 0.18033688011112042f

typedef __attribute__((ext_vector_type(8)))  short          bf16x8;
typedef __attribute__((ext_vector_type(4)))  float          f32x4;
typedef __attribute__((ext_vector_type(8)))  unsigned short u16x8;

__device__ __forceinline__ unsigned short f2bf(float f) {
  unsigned u = __builtin_bit_cast(unsigned, f);
  u += 0x7fffu + ((u >> 16) & 1u);          // round-to-nearest-even
  return (unsigned short)(u >> 16);
}

__device__ __forceinline__ f32x4 vmax4(f32x4 a, f32x4 b) {
  f32x4 r;
  r[0]=fmaxf(a[0],b[0]); r[1]=fmaxf(a[1],b[1]);
  r[2]=fmaxf(a[2],b[2]); r[3]=fmaxf(a[3],b[3]);
  return r;
}

__device__ __forceinline__ void async_copy16(void* lds, const void* g) {
  __builtin_amdgcn_global_load_lds(
      (const __attribute__((address_space(1))) unsigned int*)g,
      (__attribute__((address_space(3))) unsigned int*)lds, 16, 0, 0);
}

// ---------------------------------------------------------------- convert x
__global__ void convert_x_kernel(const float* __restrict__ x,
                                 unsigned short* __restrict__ xb) {
  int i = blockIdx.x * 256 + threadIdx.x;
  const f32x4* xv = reinterpret_cast<const f32x4*>(x);
  f32x4 a = xv[2*i];
  f32x4 b = xv[2*i + 1];
  u16x8 r;
  r[0]=f2bf(a[0]); r[1]=f2bf(a[1]); r[2]=f2bf(a[2]); r[3]=f2bf(a[3]);
  r[4]=f2bf(b[0]); r[5]=f2bf(b[1]); r[6]=f2bf(b[2]); r[7]=f2bf(b[3]);
  reinterpret_cast<u16x8*>(xb)[i] = r;
}

// --------------------------------------- transpose + permute + convert W
__global__ void transpose_w_kernel(const float* __restrict__ W,
                                   unsigned short* __restrict__ Wt) {
  __shared__ float tile[64][65];
  int j0 = blockIdx.x * 64;
  int k0 = blockIdx.y * 64;
  int tid = threadIdx.x;
  int lr = tid >> 6;
  int lc = tid & 63;
  #pragma unroll
  for (int i = 0; i < 16; ++i) {
    int r = i*4 + lr;
    tile[r][lc] = W[(size_t)(k0 + r)*NTOT + j0 + lc];
  }
  __syncthreads();
  #pragma unroll
  for (int i = 0; i < 16; ++i) {
    int jr = i*4 + lr;
    int j  = j0 + jr;
    int oc = (j % 3)*DMODEL + (j / 3);
    Wt[(size_t)oc*KTOT + k0 + lc] = f2bf(tile[lc][jr]);
  }
}

// ---------------------------------------------------------------- QKV GEMM
// R11 structure (kept): A+B double-buffered at BK=32, one barrier/iter,
// T2 swizzle (seg ^ ((row>>1)&3)); V-epilogue LDS transpose.
#define BM 128
#define BN 128
#define BK2 32
#define NBX (NTOT/BN)    // 24
#define NBY (MTOT/BM)    // 32
#define EPSTRIDE 136     // epilogue LDS row stride (elems): b64/b128 aligned
__launch_bounds__(256)
__global__ void qkv_gemm_kernel(const unsigned short* __restrict__ xb,
                                const unsigned short* __restrict__ wt,
                                const float* __restrict__ bqkv,
                                unsigned short* __restrict__ Qb,
                                unsigned short* __restrict__ Kb,
                                unsigned short* __restrict__ Vt) {
  __shared__ __align__(16) unsigned char gsm[128*EPSTRIDE*2]; // 34816 B
  unsigned short* As = (unsigned short*)gsm;            // [2][128*32] 16 KB
  unsigned short* Bs = (unsigned short*)(gsm + 16384);  // [2][128*32] 16 KB
  unsigned short* Ep = (unsigned short*)gsm;            // epilogue transpose

  int tid = threadIdx.x;
  int w = tid >> 6, l = tid & 63;
  int m0 = blockIdx.y * BM;
  int n0 = blockIdx.x * BN;
  int ln = l & 15, lg = l >> 4;
  int wm = (w >> 1) * 64;
  int wn = (w & 1) * 64;

  f32x4 acc[4][4];
  const f32x4 zero4 = {0.f, 0.f, 0.f, 0.f};
  #pragma unroll
  for (int i = 0; i < 4; ++i)
    #pragma unroll
    for (int j = 0; j < 4; ++j) acc[i][j] = zero4;

  // stage: linear LDS dest (wave-uniform base + lane*16B), pre-swizzled src
  #define STAGE2(BUF, KT)                                                     \
  do {                                                                        \
    _Pragma("unroll")                                                         \
    for (int i = 0; i < 2; ++i) {                                             \
      int row  = i*64 + w*16 + (l >> 2);                                      \
      int seg  = (l & 3) ^ ((row >> 1) & 3);                                  \
      async_copy16(gsm + (BUF)*8192 + i*4096 + w*1024,                        \
                   &xb[(size_t)(m0 + row)*KTOT + (KT)*BK2 + seg*8]);          \
      async_copy16(gsm + 16384 + (BUF)*8192 + i*4096 + w*1024,                \
                   &wt[(size_t)(n0 + row)*KTOT + (KT)*BK2 + seg*8]);          \
    }                                                                         \
  } while (0)

  STAGE2(0, 0);
  asm volatile("s_waitcnt vmcnt(0)" ::: "memory");
  __syncthreads();

  for (int kt = 0; kt < KTOT/BK2; ++kt) {
    int cur = kt & 1;
    if (kt < KTOT/BK2 - 1) STAGE2(cur ^ 1, kt + 1);   // covered by compute

    bf16x8 af[4], bfr[4];
    #pragma unroll
    for (int mi = 0; mi < 4; ++mi) {
      int ra = wm + mi*16 + ln;
      af[mi] = *reinterpret_cast<const bf16x8*>(
          &As[cur*4096 + ra*BK2 + ((lg ^ ((ra >> 1) & 3)) << 3)]);
    }
    #pragma unroll
    for (int ni = 0; ni < 4; ++ni) {
      int rb = wn + ni*16 + ln;
      bfr[ni] = *reinterpret_cast<const bf16x8*>(
          &Bs[cur*4096 + rb*BK2 + ((lg ^ ((rb >> 1) & 3)) << 3)]);
    }
    #pragma unroll
    for (int mi = 0; mi < 4; ++mi)
      #pragma unroll
      for (int ni = 0; ni < 4; ++ni)
        acc[mi][ni] = __builtin_amdgcn_mfma_f32_16x16x32_bf16(af[mi], bfr[ni], acc[mi][ni], 0, 0, 0);

    __syncthreads();   // drains prefetch (implicit vmcnt0) + LDS reads
  }
  #undef STAGE2

  int r4 = lg * 4;
  if (n0 >= 2*DMODEL) {
    // ---- V block (uniform c==2): LDS transpose -> coalesced Vt stores
    int hd0 = n0 - 2*DMODEL;
    #pragma unroll
    for (int mi = 0; mi < 4; ++mi) {
      #pragma unroll
      for (int ni = 0; ni < 4; ++ni) {
        int col = wn + ni*16 + ln;                 // hd_local
        float bias = bqkv[(hd0 + col)*3 + 2];
        int rb = wm + mi*16 + r4;                  // t_local base (mult of 4)
        ushort4 pk4;
        pk4.x = f2bf(acc[mi][ni][0] + bias);
        pk4.y = f2bf(acc[mi][ni][1] + bias);
        pk4.z = f2bf(acc[mi][ni][2] + bias);
        pk4.w = f2bf(acc[mi][ni][3] + bias);
        *reinterpret_cast<ushort4*>(&Ep[col*EPSTRIDE + rb]) = pk4;
      }
    }
    __syncthreads();
    int n = m0 >> 11, t0 = m0 & 2047;
    #pragma unroll
    for (int pass = 0; pass < 8; ++pass) {
      int hdl = pass*16 + (tid >> 4);
      int seg = tid & 15;
      bf16x8 v = *reinterpret_cast<const bf16x8*>(&Ep[hdl*EPSTRIDE + seg*8]);
      int hd = hd0 + hdl, h = hd >> 6, d = hd & 63;
      *reinterpret_cast<bf16x8*>(
          &Vt[(((size_t)(n*NHEADS + h)*HDIM + d) << 11) + t0 + seg*8]) = v;
    }
  } else {
    // ---- Q/K blocks (c==0/1): 32B-contiguous per 16-lane group
    #pragma unroll
    for (int mi = 0; mi < 4; ++mi) {
      #pragma unroll
      for (int ni = 0; ni < 4; ++ni) {
        int nc = n0 + wn + ni*16 + ln;
        int c  = nc >> 10;
        int hd = nc & 1023;
        int h = hd >> 6, d = hd & 63;
        float bias = bqkv[hd*3 + c];
        float qs = (c == 0) ? QSCALE : 1.0f;   // fold softmax scale into Q
        #pragma unroll
        for (int j = 0; j < 4; ++j) {
          int m = m0 + wm + mi*16 + r4 + j;
          int n = m >> 11, t = m & 2047;
          unsigned short val = f2bf((acc[mi][ni][j] + bias) * qs);
          size_t nh = (size_t)(n*NHEADS + h);
          if (c == 0) Qb[((nh*SEQ + t) << 6) + d] = val;
          else        Kb[((nh*SEQ + t) << 6) + d] = val;
        }
      }
    }
  }
}

// ---------------------------------------------------------------- attention
// R17: V back in LDS (R16's V-from-global was latency-bound: 162us).
// LDS-BW attack instead: each wave owns 32 q-rows (TWO Q fragment sets) so
// the K/V fragment reads (the dominant LDS term, independent of q-count)
// amortize over 2x MFMA. Per-32q LDS: 44KB -> 28KB. Block = 4 waves =
// 128 q-rows; grid 512; LDS 55.3KB -> 2 blocks/CU. All validated pieces
// kept: fragment maps, rule-21 swizzle, per-set defer-max, cvt_pk P-pack,
// 2-buffer staging + vmcnt(0) barrier, final aliasing barrier.
#define PROW    88                  // P row stride, bf16 elems (176 B)
#define POFF    32768               // P regions start (after 2 staging bufs)
#define PBYTES  5632                // 32 rows x 176 B per wave
#define OREGION 8704                // epilogue obuf: 32 x 68 f32 (reuses LDS)
__launch_bounds__(256)
__global__ void attn_kernel(const unsigned short* __restrict__ Qb,
                            const unsigned short* __restrict__ Kb,
                            const unsigned short* __restrict__ Vt,
                            float* __restrict__ out) {
  __shared__ __align__(16) unsigned char smem[POFF + 4*PBYTES]; // 55296 B
  int tid = threadIdx.x;
  int w = tid >> 6, l = tid & 63;
  int ln = l & 15, lg = l >> 4;

  unsigned short* Pw  = (unsigned short*)(smem + POFF + w * PBYTES);
  float*          obw = (float*)         (smem + w * OREGION); // post-loop only

  // XCD clustering: 512 blocks, 8 XCDs -> each XCD owns 4 heads
  int fid  = blockIdx.x;
  int xcd  = fid & 7, idx = fid >> 3;       // idx 0..63
  int bh   = xcd * 4 + (idx >> 4);          // 0..31
  int qblk = idx & 15;                      // 0..15 (128 q-rows each)
  int q0   = qblk * 128 + w * 32;           // wave owns 32 q-rows

  const unsigned short* Qh = Qb + (size_t)bh * SEQ * HDIM;
  const unsigned short* Kh = Kb + (size_t)bh * SEQ * HDIM;
  const unsigned short* Vh = Vt + (size_t)bh * HDIM * SEQ;

  // Q B-fragments: set s covers q = q0 + s*16 + ln, d-windows dw=0,1
  bf16x8 qf0[2], qf1[2];
  #pragma unroll
  for (int dw = 0; dw < 2; ++dw) {
    qf0[dw] = *reinterpret_cast<const bf16x8*>(&Qh[(size_t)(q0      + ln)*HDIM + dw*32 + lg*8]);
    qf1[dw] = *reinterpret_cast<const bf16x8*>(&Qh[(size_t)(q0 + 16 + ln)*HDIM + dw*32 + lg*8]);
  }

  const f32x4 zero4 = {0.f, 0.f, 0.f, 0.f};
  f32x4 o0[4], o1[4];
  #pragma unroll
  for (int db = 0; db < 4; ++db) { o0[db] = zero4; o1[db] = zero4; }
  f32x4 psum0 = zero4, psum1 = zero4;
  float mrow0 = -INFINITY, mrow1 = -INFINITY;

  int xorE = (ln & 7) << 3;        // element-index XOR for swizzled ds_read
  int coff0 = (((     lg*8) ^ xorE)) * 2;   // d-window 0 column bytes
  int coff1 = (((32 + lg*8) ^ xorE)) * 2;   // d-window 1 column bytes
  int rbyte = ln * 128;                     // fragment row base bytes
  const unsigned char* kv0 = smem + rbyte + coff0;
  const unsigned char* kv1 = smem + rbyte + coff1;

  // STAGE one 64-key tile (K 8KB + V 8KB) with 256 threads: 2 calls each
  #define STAGE(BUF, KEY0)                                                    \
  do {                                                                        \
    _Pragma("unroll")                                                         \
    for (int c = 0; c < 2; ++c) {                                             \
      int row = c*32 + w*8 + (l >> 3);                                        \
      int seg = (l & 7) ^ (row & 7);                                          \
      async_copy16(smem + (BUF)*16384 + c*4096 + w*1024,                      \
                   &Kh[(size_t)((KEY0) + row)*HDIM + seg*8]);                 \
      async_copy16(smem + (BUF)*16384 + 8192 + c*4096 + w*1024,               \
                   &Vh[(size_t)row*SEQ + (KEY0) + seg*8]);                    \
    }                                                                         \
  } while (0)

  #define ENDTILE                                                             \
  do {                                                                        \
    asm volatile("s_waitcnt vmcnt(0)" ::: "memory");                          \
    __builtin_amdgcn_s_barrier();                                             \
    asm volatile("" ::: "memory");                                            \
  } while (0)

  // one 64-key tile from K/V buffer CUR; optional prefetch into NXT
  #define TILE(CUR, DOSTAGE, NXT, NKEY)                                       \
  do {                                                                        \
    if (DOSTAGE) STAGE(NXT, NKEY);                                            \
    f32x4 s0_[4], s1_[4];                                                     \
    __builtin_amdgcn_s_setprio(1);                                            \
    _Pragma("unroll")                                                         \
    for (int kb = 0; kb < 4; ++kb) {                                          \
      bf16x8 k0 = *reinterpret_cast<const bf16x8*>(kv0 + (CUR)*16384 + kb*2048);\
      bf16x8 k1 = *reinterpret_cast<const bf16x8*>(kv1 + (CUR)*16384 + kb*2048);\
      f32x4 ta = __builtin_amdgcn_mfma_f32_16x16x32_bf16(k0, qf0[0], zero4, 0, 0, 0);\
      s0_[kb]  = __builtin_amdgcn_mfma_f32_16x16x32_bf16(k1, qf0[1], ta,    0, 0, 0);\
      f32x4 tb = __builtin_amdgcn_mfma_f32_16x16x32_bf16(k0, qf1[0], zero4, 0, 0, 0);\
      s1_[kb]  = __builtin_amdgcn_mfma_f32_16x16x32_bf16(k1, qf1[1], tb,    0, 0, 0);\
    }                                                                         \
    __builtin_amdgcn_s_setprio(0);                                            \
    /* per-set local max */                                                   \
    f32x4 m4a = vmax4(vmax4(s0_[0], s0_[1]), vmax4(s0_[2], s0_[3]));          \
    f32x4 m4b = vmax4(vmax4(s1_[0], s1_[1]), vmax4(s1_[2], s1_[3]));          \
    float lm0 = fmaxf(fmaxf(fmaxf(m4a[0], m4a[1]), m4a[2]), m4a[3]);          \
    float lm1 = fmaxf(fmaxf(fmaxf(m4b[0], m4b[1]), m4b[2]), m4b[3]);          \
    /* T13 defer-max (wave-uniform across both sets) */                       \
    if (!__all((lm0 <= mrow0 + 8.f) && (lm1 <= mrow1 + 8.f))) {               \
      float pm0 = lm0, pm1 = lm1;                                             \
      pm0 = fmaxf(pm0, __shfl_xor(pm0, 16));                                  \
      pm0 = fmaxf(pm0, __shfl_xor(pm0, 32));                                  \
      pm1 = fmaxf(pm1, __shfl_xor(pm1, 16));                                  \
      pm1 = fmaxf(pm1, __shfl_xor(pm1, 32));                                  \
      float mn0 = fmaxf(mrow0, pm0), mn1 = fmaxf(mrow1, pm1);                 \
      float sc0 = __builtin_amdgcn_exp2f(mrow0 - mn0);                        \
      float sc1 = __builtin_amdgcn_exp2f(mrow1 - mn1);                        \
      mrow0 = mn0; mrow1 = mn1;                                               \
      psum0 *= sc0; psum1 *= sc1;                                             \
      _Pragma("unroll")                                                       \
      for (int db = 0; db < 4; ++db)                                          \
        _Pragma("unroll")                                                     \
        for (int r = 0; r < 4; ++r) { o0[db][r] *= sc0; o1[db][r] *= sc1; }   \
    }                                                                         \
    /* P = exp2(S - m); per-lane partial sums */                              \
    _Pragma("unroll")                                                         \
    for (int kb = 0; kb < 4; ++kb) {                                          \
      _Pragma("unroll")                                                       \
      for (int r = 0; r < 4; ++r) {                                           \
        s0_[kb][r] = __builtin_amdgcn_exp2f(s0_[kb][r] - mrow0);              \
        s1_[kb][r] = __builtin_amdgcn_exp2f(s1_[kb][r] - mrow1);              \
      }                                                                       \
      psum0 += s0_[kb];                                                       \
      psum1 += s1_[kb];                                                       \
    }                                                                         \
    /* P -> LDS via cvt_pk (rows ln and 16+ln) */                             \
    _Pragma("unroll")                                                         \
    for (int kb = 0; kb < 4; ++kb) {                                          \
      uint2 pka, pkb;                                                         \
      asm("v_cvt_pk_bf16_f32 %0, %1, %2" : "=v"(pka.x) : "v"(s0_[kb][0]), "v"(s0_[kb][1]));\
      asm("v_cvt_pk_bf16_f32 %0, %1, %2" : "=v"(pka.y) : "v"(s0_[kb][2]), "v"(s0_[kb][3]));\
      asm("v_cvt_pk_bf16_f32 %0, %1, %2" : "=v"(pkb.x) : "v"(s1_[kb][0]), "v"(s1_[kb][1]));\
      asm("v_cvt_pk_bf16_f32 %0, %1, %2" : "=v"(pkb.y) : "v"(s1_[kb][2]), "v"(s1_[kb][3]));\
      *reinterpret_cast<uint2*>(&Pw[(     ln)*PROW + kb*16 + 4*lg]) = pka;    \
      *reinterpret_cast<uint2*>(&Pw[(16 + ln)*PROW + kb*16 + 4*lg]) = pkb;    \
    }                                                                         \
    /* PV: V frags read once, consumed by both q-sets */                      \
    _Pragma("unroll")                                                         \
    for (int kw = 0; kw < 2; ++kw) {                                          \
      bf16x8 pb0 = *reinterpret_cast<const bf16x8*>(&Pw[(     ln)*PROW + kw*32 + lg*8]);\
      bf16x8 pb1 = *reinterpret_cast<const bf16x8*>(&Pw[(16 + ln)*PROW + kw*32 + lg*8]);\
      const unsigned char* vb = (kw == 0) ? kv0 : kv1;                        \
      __builtin_amdgcn_s_setprio(1);                                          \
      _Pragma("unroll")                                                       \
      for (int db = 0; db < 4; ++db) {                                        \
        bf16x8 vfr = *reinterpret_cast<const bf16x8*>(                        \
            vb + (CUR)*16384 + 8192 + db*2048);                               \
        o0[db] = __builtin_amdgcn_mfma_f32_16x16x32_bf16(vfr, pb0, o0[db], 0, 0, 0);\
        o1[db] = __builtin_amdgcn_mfma_f32_16x16x32_bf16(vfr, pb1, o1[db], 0, 0, 0);\
      }                                                                       \
      __builtin_amdgcn_s_setprio(0);                                          \
    }                                                                         \
    ENDTILE;                                                                  \
  } while (0)

  // ---- prologue + main loop (2-buffer, prefetch distance 1)
  STAGE(0, 0);
  ENDTILE;
  for (int t = 0; t < 30; t += 2) {
    TILE(0, 1, 1, (t + 1) * 64);
    TILE(1, 1, 0, (t + 2) * 64);
  }
  TILE(0, 1, 1, 31 * 64);   // tile 30 (buf0), stage tile 31 -> buf1
  TILE(1, 0, 0, 0);         // tile 31 (buf1), no stage

  // obw aliases staging + P LDS — all waves must finish reads first.
  __syncthreads();

  #undef TILE
  #undef ENDTILE
  #undef STAGE

  // ---- post-loop: per-set row-sum reduce, normalize, transpose, store
  float ls0 = (psum0[0] + psum0[1]) + (psum0[2] + psum0[3]);
  float ls1 = (psum1[0] + psum1[1]) + (psum1[2] + psum1[3]);
  ls0 += __shfl_xor(ls0, 16);
  ls0 += __shfl_xor(ls0, 32);
  ls1 += __shfl_xor(ls1, 16);
  ls1 += __shfl_xor(ls1, 32);
  float inv0 = 1.f / ls0, inv1 = 1.f / ls1;

  #pragma unroll
  for (int db = 0; db < 4; ++db)
    #pragma unroll
    for (int r = 0; r < 4; ++r) {
      obw[(     ln)*68 + db*16 + 4*lg + r] = o0[db][r] * inv0;
      obw[(16 + ln)*68 + db*16 + 4*lg + r] = o1[db][r] * inv1;
    }
  asm volatile("s_waitcnt lgkmcnt(0)" ::: "memory");
  int n = bh >> 4, h = bh & 15;
  #pragma unroll
  for (int p = 0; p < 8; ++p) {
    int q = p*4 + lg;                      // 0..31 within wave's rows
    f32x4 vv = *reinterpret_cast<const f32x4*>(&obw[q*68 + ln*4]);
    *reinterpret_cast<f32x4*>(
        &out[((size_t)(n*SEQ + q0 + q))*DMODEL + h*HDIM + ln*4]) = vv;
  }
}

// ---------------------------------------------------------------- launcher
extern "C" void kernel_launch(void* const* d_in, const int* in_sizes, int n_in,
                              void* d_out, int out_size, void* d_ws, size_t ws_size,
                              hipStream_t stream) {
  const float* x    = (const float*)d_in[0];
  // d_in[1] = mask: constant shift along query axis inside softmax -> no-op
  const float* Wq   = (const float*)d_in[2];
  const float* bq   = (const float*)d_in[3];
  float* out = (float*)d_out;

  unsigned short* xb = (unsigned short*)d_ws;                    // [4096][1024]
  unsigned short* wt = xb + (size_t)MTOT*KTOT;                   // [3072][1024]
  unsigned short* Qb = wt + (size_t)NTOT*KTOT;                   // [32][2048][64]
  unsigned short* Kb = Qb + (size_t)NB*NHEADS*SEQ*HDIM;          // [32][2048][64]
  unsigned short* Vt = Kb + (size_t)NB*NHEADS*SEQ*HDIM;          // [32][64][2048]

  convert_x_kernel<<<(MTOT*KTOT/8)/256, 256, 0, stream>>>(x, xb);
  transpose_w_kernel<<<dim3(NTOT/64, KTOT/64), 256, 0, stream>>>(Wq, wt);
  qkv_gemm_kernel<<<dim3(NBX, NBY), 256, 0, stream>>>(xb, wt, bq, Qb, Kb, Vt);
  attn_kernel<<<512, 256, 0, stream>>>(Qb, Kb, Vt, out);
}

// Round 18
// 107.564 us; speedup vs baseline: 1.9477x; 1.0779x over previous
//
#include <hip/hip_runtime.h>
#include <hip/hip_bf16.h>
#include <stdint.h>

// Sizes (fixed for this problem)
#define NHEADS 16
#define HDIM   64
#define DMODEL 1024
#define SEQ    2048
#define NB     2
#define MTOT   (NB*SEQ)     // 4096 rows of x
#define NTOT   (3*DMODEL)   // 3072 qkv cols
#define KTOT   DMODEL       // 1024

// fold (1/8)*log2(e) into Q so softmax runs in exp2 domain
#define QSCALE 0.18033688011112042f

typedef __attribute__((ext_vector_type(8)))  short          bf16x8;
typedef __attribute__((ext_vector_type(4)))  float          f32x4;
typedef __attribute__((ext_vector_type(8)))  unsigned short u16x8;

__device__ __forceinline__ unsigned short f2bf(float f) {
  unsigned u = __builtin_bit_cast(unsigned, f);
  u += 0x7fffu + ((u >> 16) & 1u);          // round-to-nearest-even
  return (unsigned short)(u >> 16);
}

__device__ __forceinline__ f32x4 vmax4(f32x4 a, f32x4 b) {
  f32x4 r;
  r[0]=fmaxf(a[0],b[0]); r[1]=fmaxf(a[1],b[1]);
  r[2]=fmaxf(a[2],b[2]); r[3]=fmaxf(a[3],b[3]);
  return r;
}

__device__ __forceinline__ void async_copy16(void* lds, const void* g) {
  __builtin_amdgcn_global_load_lds(
      (const __attribute__((address_space(1))) unsigned int*)g,
      (__attribute__((address_space(3))) unsigned int*)lds, 16, 0, 0);
}

// ---------------------------------------------------------------- convert x
__global__ void convert_x_kernel(const float* __restrict__ x,
                                 unsigned short* __restrict__ xb) {
  int i = blockIdx.x * 256 + threadIdx.x;
  const f32x4* xv = reinterpret_cast<const f32x4*>(x);
  f32x4 a = xv[2*i];
  f32x4 b = xv[2*i + 1];
  u16x8 r;
  r[0]=f2bf(a[0]); r[1]=f2bf(a[1]); r[2]=f2bf(a[2]); r[3]=f2bf(a[3]);
  r[4]=f2bf(b[0]); r[5]=f2bf(b[1]); r[6]=f2bf(b[2]); r[7]=f2bf(b[3]);
  reinterpret_cast<u16x8*>(xb)[i] = r;
}

// --------------------------------------- transpose + permute + convert W
__global__ void transpose_w_kernel(const float* __restrict__ W,
                                   unsigned short* __restrict__ Wt) {
  __shared__ float tile[64][65];
  int j0 = blockIdx.x * 64;
  int k0 = blockIdx.y * 64;
  int tid = threadIdx.x;
  int lr = tid >> 6;
  int lc = tid & 63;
  #pragma unroll
  for (int i = 0; i < 16; ++i) {
    int r = i*4 + lr;
    tile[r][lc] = W[(size_t)(k0 + r)*NTOT + j0 + lc];
  }
  __syncthreads();
  #pragma unroll
  for (int i = 0; i < 16; ++i) {
    int jr = i*4 + lr;
    int j  = j0 + jr;
    int oc = (j % 3)*DMODEL + (j / 3);
    Wt[(size_t)oc*KTOT + k0 + lc] = f2bf(tile[lc][jr]);
  }
}

// ---------------------------------------------------------------- QKV GEMM
// R11 structure (kept): A+B double-buffered at BK=32, one barrier/iter,
// T2 swizzle (seg ^ ((row>>1)&3)); V-epilogue LDS transpose.
#define BM 128
#define BN 128
#define BK2 32
#define NBX (NTOT/BN)    // 24
#define NBY (MTOT/BM)    // 32
#define EPSTRIDE 136     // epilogue LDS row stride (elems): b64/b128 aligned
__launch_bounds__(256)
__global__ void qkv_gemm_kernel(const unsigned short* __restrict__ xb,
                                const unsigned short* __restrict__ wt,
                                const float* __restrict__ bqkv,
                                unsigned short* __restrict__ Qb,
                                unsigned short* __restrict__ Kb,
                                unsigned short* __restrict__ Vt) {
  __shared__ __align__(16) unsigned char gsm[128*EPSTRIDE*2]; // 34816 B
  unsigned short* As = (unsigned short*)gsm;            // [2][128*32] 16 KB
  unsigned short* Bs = (unsigned short*)(gsm + 16384);  // [2][128*32] 16 KB
  unsigned short* Ep = (unsigned short*)gsm;            // epilogue transpose

  int tid = threadIdx.x;
  int w = tid >> 6, l = tid & 63;
  int m0 = blockIdx.y * BM;
  int n0 = blockIdx.x * BN;
  int ln = l & 15, lg = l >> 4;
  int wm = (w >> 1) * 64;
  int wn = (w & 1) * 64;

  f32x4 acc[4][4];
  const f32x4 zero4 = {0.f, 0.f, 0.f, 0.f};
  #pragma unroll
  for (int i = 0; i < 4; ++i)
    #pragma unroll
    for (int j = 0; j < 4; ++j) acc[i][j] = zero4;

  // stage: linear LDS dest (wave-uniform base + lane*16B), pre-swizzled src
  #define STAGE2(BUF, KT)                                                     \
  do {                                                                        \
    _Pragma("unroll")                                                         \
    for (int i = 0; i < 2; ++i) {                                             \
      int row  = i*64 + w*16 + (l >> 2);                                      \
      int seg  = (l & 3) ^ ((row >> 1) & 3);                                  \
      async_copy16(gsm + (BUF)*8192 + i*4096 + w*1024,                        \
                   &xb[(size_t)(m0 + row)*KTOT + (KT)*BK2 + seg*8]);          \
      async_copy16(gsm + 16384 + (BUF)*8192 + i*4096 + w*1024,                \
                   &wt[(size_t)(n0 + row)*KTOT + (KT)*BK2 + seg*8]);          \
    }                                                                         \
  } while (0)

  STAGE2(0, 0);
  asm volatile("s_waitcnt vmcnt(0)" ::: "memory");
  __syncthreads();

  for (int kt = 0; kt < KTOT/BK2; ++kt) {
    int cur = kt & 1;
    if (kt < KTOT/BK2 - 1) STAGE2(cur ^ 1, kt + 1);   // covered by compute

    bf16x8 af[4], bfr[4];
    #pragma unroll
    for (int mi = 0; mi < 4; ++mi) {
      int ra = wm + mi*16 + ln;
      af[mi] = *reinterpret_cast<const bf16x8*>(
          &As[cur*4096 + ra*BK2 + ((lg ^ ((ra >> 1) & 3)) << 3)]);
    }
    #pragma unroll
    for (int ni = 0; ni < 4; ++ni) {
      int rb = wn + ni*16 + ln;
      bfr[ni] = *reinterpret_cast<const bf16x8*>(
          &Bs[cur*4096 + rb*BK2 + ((lg ^ ((rb >> 1) & 3)) << 3)]);
    }
    #pragma unroll
    for (int mi = 0; mi < 4; ++mi)
      #pragma unroll
      for (int ni = 0; ni < 4; ++ni)
        acc[mi][ni] = __builtin_amdgcn_mfma_f32_16x16x32_bf16(af[mi], bfr[ni], acc[mi][ni], 0, 0, 0);

    __syncthreads();   // drains prefetch (implicit vmcnt0) + LDS reads
  }
  #undef STAGE2

  int r4 = lg * 4;
  if (n0 >= 2*DMODEL) {
    // ---- V block (uniform c==2): LDS transpose -> coalesced Vt stores
    int hd0 = n0 - 2*DMODEL;
    #pragma unroll
    for (int mi = 0; mi < 4; ++mi) {
      #pragma unroll
      for (int ni = 0; ni < 4; ++ni) {
        int col = wn + ni*16 + ln;                 // hd_local
        float bias = bqkv[(hd0 + col)*3 + 2];
        int rb = wm + mi*16 + r4;                  // t_local base (mult of 4)
        ushort4 pk4;
        pk4.x = f2bf(acc[mi][ni][0] + bias);
        pk4.y = f2bf(acc[mi][ni][1] + bias);
        pk4.z = f2bf(acc[mi][ni][2] + bias);
        pk4.w = f2bf(acc[mi][ni][3] + bias);
        *reinterpret_cast<ushort4*>(&Ep[col*EPSTRIDE + rb]) = pk4;
      }
    }
    __syncthreads();
    int n = m0 >> 11, t0 = m0 & 2047;
    #pragma unroll
    for (int pass = 0; pass < 8; ++pass) {
      int hdl = pass*16 + (tid >> 4);
      int seg = tid & 15;
      bf16x8 v = *reinterpret_cast<const bf16x8*>(&Ep[hdl*EPSTRIDE + seg*8]);
      int hd = hd0 + hdl, h = hd >> 6, d = hd & 63;
      *reinterpret_cast<bf16x8*>(
          &Vt[(((size_t)(n*NHEADS + h)*HDIM + d) << 11) + t0 + seg*8]) = v;
    }
  } else {
    // ---- Q/K blocks (c==0/1): 32B-contiguous per 16-lane group
    #pragma unroll
    for (int mi = 0; mi < 4; ++mi) {
      #pragma unroll
      for (int ni = 0; ni < 4; ++ni) {
        int nc = n0 + wn + ni*16 + ln;
        int c  = nc >> 10;
        int hd = nc & 1023;
        int h = hd >> 6, d = hd & 63;
        float bias = bqkv[hd*3 + c];
        float qs = (c == 0) ? QSCALE : 1.0f;   // fold softmax scale into Q
        #pragma unroll
        for (int j = 0; j < 4; ++j) {
          int m = m0 + wm + mi*16 + r4 + j;
          int n = m >> 11, t = m & 2047;
          unsigned short val = f2bf((acc[mi][ni][j] + bias) * qs);
          size_t nh = (size_t)(n*NHEADS + h);
          if (c == 0) Qb[((nh*SEQ + t) << 6) + d] = val;
          else        Kb[((nh*SEQ + t) << 6) + d] = val;
        }
      }
    }
  }
}

// ---------------------------------------------------------------- attention
// R18 = R15 verbatim (best known: attn ~55.5us). T15 att[2] S-double-
// pipeline + aliasing barrier. Iteration t: STAGE(t+1) | QK(t) MFMA |
// softmax(t-1) VALU | PV(t-1). 3 buffers {t-1, t, t+1}; writer (t+1)%3
// disjoint from both readers; final __syncthreads before obw reuse.
#define PROW    88                  // P row stride, bf16 elems (176 B)
#define POFF    49152               // P regions start (after 3 staging bufs)
#define PBYTES  2816                // 16 rows x 176 B per wave
#define OREGION 4352                // epilogue obuf: 16 x 68 f32 (reuses staging)
__launch_bounds__(512)
__global__ void attn_kernel(const unsigned short* __restrict__ Qb,
                            const unsigned short* __restrict__ Kb,
                            const unsigned short* __restrict__ Vt,
                            float* __restrict__ out) {
  __shared__ __align__(16) unsigned char smem[POFF + 8*PBYTES]; // 71680 B
  int tid = threadIdx.x;
  int w = tid >> 6, l = tid & 63;
  int ln = l & 15, lg = l >> 4;

  unsigned short* Pw  = (unsigned short*)(smem + POFF + w * PBYTES);
  float*          obw = (float*)         (smem + w * OREGION); // post-loop only

  // XCD clustering: 512 blocks, 8 XCDs -> each XCD owns 4 heads
  int fid  = blockIdx.x;
  int xcd  = fid & 7, idx = fid >> 3;       // idx 0..63
  int bh   = xcd * 4 + (idx >> 4);          // 0..31
  int qblk = idx & 15;                      // 0..15 (128 q-rows each)
  int q0   = qblk * 128 + w * 16;

  const unsigned short* Qh = Qb + (size_t)bh * SEQ * HDIM;
  const unsigned short* Kh = Kb + (size_t)bh * SEQ * HDIM;
  const unsigned short* Vh = Vt + (size_t)bh * HDIM * SEQ;

  // staging mapping: 512 threads cover one 64x64 bf16 tile in ONE call
  int srow = w*8 + (l >> 3);      // row 0..63
  int sseg = (l & 7) ^ (srow & 7);// inverse-swizzled 16B segment

  // Q B-fragments (col = q = ln), d-windows dw=0,1
  bf16x8 qf[2];
  #pragma unroll
  for (int dw = 0; dw < 2; ++dw)
    qf[dw] = *reinterpret_cast<const bf16x8*>(&Qh[(size_t)(q0 + ln)*HDIM + dw*32 + lg*8]);

  const f32x4 zero4 = {0.f, 0.f, 0.f, 0.f};
  f32x4 o[4];
  #pragma unroll
  for (int db = 0; db < 4; ++db) o[db] = zero4;
  f32x4 psum4 = zero4;
  float mrow = -INFINITY;
  f32x4 sA[4], sB[4];

  int xorE = (ln & 7) << 3;        // element-index XOR for swizzled ds_read
  int coff0 = (((     lg*8) ^ xorE)) * 2;   // d-window 0 column bytes
  int coff1 = (((32 + lg*8) ^ xorE)) * 2;   // d-window 1 column bytes
  int rbyte = ln * 128;                     // fragment row base bytes
  const unsigned char* kv0 = smem + rbyte + coff0;
  const unsigned char* kv1 = smem + rbyte + coff1;

  // STAGE one 64-key tile into buffer BUF: K[key][d] + V[d][key]
  #define STAGE(BUF, KEY0)                                                    \
  do {                                                                        \
    async_copy16(smem + (BUF)*16384 + w*1024,                                 \
                 &Kh[(size_t)((KEY0) + srow)*HDIM + sseg*8]);                 \
    async_copy16(smem + (BUF)*16384 + 8192 + w*1024,                          \
                 &Vh[(size_t)srow*SEQ + (KEY0) + sseg*8]);                    \
  } while (0)

  // QK^T for tile in buffer CUR -> SCUR (pure MFMA + ds_read stream)
  #define QKT(CUR, SCUR)                                                      \
  do {                                                                        \
    _Pragma("unroll")                                                         \
    for (int kb = 0; kb < 4; ++kb) {                                          \
      bf16x8 k0 = *reinterpret_cast<const bf16x8*>(kv0 + (CUR)*16384 + kb*2048);\
      bf16x8 k1 = *reinterpret_cast<const bf16x8*>(kv1 + (CUR)*16384 + kb*2048);\
      f32x4 t0 = __builtin_amdgcn_mfma_f32_16x16x32_bf16(k0, qf[0], zero4, 0, 0, 0);\
      SCUR[kb] = __builtin_amdgcn_mfma_f32_16x16x32_bf16(k1, qf[1], t0,    0, 0, 0);\
    }                                                                         \
  } while (0)

  // softmax on SPREV + PV with V from buffer PRV (VALU stream + PV MFMAs)
  #define SMPV(SPREV, PRV)                                                    \
  do {                                                                        \
    f32x4 m4 = vmax4(vmax4(SPREV[0], SPREV[1]), vmax4(SPREV[2], SPREV[3]));   \
    float localmax = fmaxf(fmaxf(fmaxf(m4[0], m4[1]), m4[2]), m4[3]);         \
    if (!__all(localmax <= mrow + 8.f)) {                                     \
      float pm = localmax;                                                    \
      pm = fmaxf(pm, __shfl_xor(pm, 16));                                     \
      pm = fmaxf(pm, __shfl_xor(pm, 32));                                     \
      float mn  = fmaxf(mrow, pm);                                            \
      float scl = __builtin_amdgcn_exp2f(mrow - mn);                          \
      mrow = mn;                                                              \
      psum4 *= scl;                                                           \
      _Pragma("unroll")                                                       \
      for (int db = 0; db < 4; ++db)                                          \
        _Pragma("unroll")                                                     \
        for (int r = 0; r < 4; ++r) o[db][r] *= scl;                          \
    }                                                                         \
    _Pragma("unroll")                                                         \
    for (int kb = 0; kb < 4; ++kb) {                                          \
      _Pragma("unroll")                                                       \
      for (int r = 0; r < 4; ++r)                                             \
        SPREV[kb][r] = __builtin_amdgcn_exp2f(SPREV[kb][r] - mrow);           \
      psum4 += SPREV[kb];                                                     \
    }                                                                         \
    _Pragma("unroll")                                                         \
    for (int kb = 0; kb < 4; ++kb) {                                          \
      uint2 pk;                                                               \
      asm("v_cvt_pk_bf16_f32 %0, %1, %2" : "=v"(pk.x) : "v"(SPREV[kb][0]), "v"(SPREV[kb][1]));\
      asm("v_cvt_pk_bf16_f32 %0, %1, %2" : "=v"(pk.y) : "v"(SPREV[kb][2]), "v"(SPREV[kb][3]));\
      *reinterpret_cast<uint2*>(&Pw[ln*PROW + kb*16 + 4*lg]) = pk;            \
    }                                                                         \
    _Pragma("unroll")                                                         \
    for (int kw = 0; kw < 2; ++kw) {                                          \
      bf16x8 pb = *reinterpret_cast<const bf16x8*>(&Pw[ln*PROW + kw*32 + lg*8]);\
      const unsigned char* vb = (kw == 0) ? kv0 : kv1;                        \
      __builtin_amdgcn_s_setprio(1);                                          \
      _Pragma("unroll")                                                       \
      for (int db = 0; db < 4; ++db) {                                        \
        bf16x8 vfr = *reinterpret_cast<const bf16x8*>(                        \
            vb + (PRV)*16384 + 8192 + db*2048);                               \
        o[db] = __builtin_amdgcn_mfma_f32_16x16x32_bf16(vfr, pb, o[db], 0, 0, 0);\
      }                                                                       \
      __builtin_amdgcn_s_setprio(0);                                          \
    }                                                                         \
  } while (0)

  #define ENDTILE                                                             \
  do {                                                                        \
    asm volatile("s_waitcnt vmcnt(0)" ::: "memory");                          \
    __builtin_amdgcn_s_barrier();                                             \
    asm volatile("" ::: "memory");                                            \
  } while (0)

  // FULL iteration t: stage(t+1), QK(t)->SCUR, softmax+PV(t-1) from SPREV
  #define FULL(KV, CUR, PRV, NXT, SPREV, SCUR)                                \
  do {                                                                        \
    STAGE(NXT, ((KV) + 1) * 64);                                              \
    QKT(CUR, SCUR);                                                           \
    SMPV(SPREV, PRV);                                                         \
    ENDTILE;                                                                  \
  } while (0)

  // ---- prologue: tile 0 staged+computed, tile 1 staged
  STAGE(0, 0);
  ENDTILE;                 // buffer 0 ready
  STAGE(1, 64);
  QKT(0, sA);              // S(0) -> sA
  ENDTILE;                 // buffer 1 ready

  // ---- main loop t = 1..30 (6-unrolled: buffer period 3 x S period 2)
  for (int t = 1; t < 31; t += 6) {
    FULL(t + 0, 1, 0, 2, sA, sB);
    FULL(t + 1, 2, 1, 0, sB, sA);
    FULL(t + 2, 0, 2, 1, sA, sB);
    FULL(t + 3, 1, 0, 2, sB, sA);
    FULL(t + 4, 2, 1, 0, sA, sB);
    FULL(t + 5, 0, 2, 1, sB, sA);
  }

  // ---- t = 31: no stage; QK(31)->sB (buf 1), softmax+PV(30) (V buf 0)
  QKT(1, sB);
  SMPV(sA, 0);
  ENDTILE;
  // ---- final: softmax+PV(31) (V buf 1)
  SMPV(sB, 1);

  // obw aliases staging buffers 0/1 — all waves must finish their
  // V reads (buffers 0 AND 1) before any wave reuses the LDS as obw.
  __syncthreads();

  #undef FULL
  #undef ENDTILE
  #undef SMPV
  #undef QKT
  #undef STAGE

  // ---- post-loop: row-sum reduce (once), normalize, transpose, store
  float ls = (psum4[0] + psum4[1]) + (psum4[2] + psum4[3]);
  ls += __shfl_xor(ls, 16);
  ls += __shfl_xor(ls, 32);
  float inv = 1.f / ls;

  #pragma unroll
  for (int db = 0; db < 4; ++db)
    #pragma unroll
    for (int r = 0; r < 4; ++r)
      obw[ln*68 + db*16 + 4*lg + r] = o[db][r] * inv;
  asm volatile("s_waitcnt lgkmcnt(0)" ::: "memory");
  int n = bh >> 4, h = bh & 15;
  #pragma unroll
  for (int p = 0; p < 4; ++p) {
    int q = p*4 + lg;
    f32x4 vv = *reinterpret_cast<const f32x4*>(&obw[q*68 + ln*4]);
    *reinterpret_cast<f32x4*>(
        &out[((size_t)(n*SEQ + q0 + q))*DMODEL + h*HDIM + ln*4]) = vv;
  }
}

// ---------------------------------------------------------------- launcher
extern "C" void kernel_launch(void* const* d_in, const int* in_sizes, int n_in,
                              void* d_out, int out_size, void* d_ws, size_t ws_size,
                              hipStream_t stream) {
  const float* x    = (const float*)d_in[0];
  // d_in[1] = mask: constant shift along query axis inside softmax -> no-op
  const float* Wq   = (const float*)d_in[2];
  const float* bq   = (const float*)d_in[3];
  float* out = (float*)d_out;

  unsigned short* xb = (unsigned short*)d_ws;                    // [4096][1024]
  unsigned short* wt = xb + (size_t)MTOT*KTOT;                   // [3072][1024]
  unsigned short* Qb = wt + (size_t)NTOT*KTOT;                   // [32][2048][64]
  unsigned short* Kb = Qb + (size_t)NB*NHEADS*SEQ*HDIM;          // [32][2048][64]
  unsigned short* Vt = Kb + (size_t)NB*NHEADS*SEQ*HDIM;          // [32][64][2048]

  convert_x_kernel<<<(MTOT*KTOT/8)/256, 256, 0, stream>>>(x, xb);
  transpose_w_kernel<<<dim3(NTOT/64, KTOT/64), 256, 0, stream>>>(Wq, wt);
  qkv_gemm_kernel<<<dim3(NBX, NBY), 256, 0, stream>>>(xb, wt, bq, Qb, Kb, Vt);
  attn_kernel<<<512, 512, 0, stream>>>(Qb, Kb, Vt, out);
}

// Round 19
// 99.920 us; speedup vs baseline: 2.0966x; 1.0765x over previous
//
#include <hip/hip_runtime.h>
#include <hip/hip_bf16.h>
#include <stdint.h>

// Sizes (fixed for this problem)
#define NHEADS 16
#define HDIM   64
#define DMODEL 1024
#define SEQ    2048
#define NB     2
#define MTOT   (NB*SEQ)     // 4096 rows of x
#define NTOT   (3*DMODEL)   // 3072 qkv cols
#define KTOT   DMODEL       // 1024

// fold (1/8)*log2(e) into Q so softmax runs in exp2 domain
#define QSCALE 0.18033688011112042f

typedef __attribute__((ext_vector_type(8)))  short          bf16x8;
typedef __attribute__((ext_vector_type(4)))  float          f32x4;
typedef __attribute__((ext_vector_type(8)))  unsigned short u16x8;

__device__ __forceinline__ unsigned short f2bf(float f) {
  unsigned u = __builtin_bit_cast(unsigned, f);
  u += 0x7fffu + ((u >> 16) & 1u);          // round-to-nearest-even
  return (unsigned short)(u >> 16);
}

__device__ __forceinline__ f32x4 vmax4(f32x4 a, f32x4 b) {
  f32x4 r;
  r[0]=fmaxf(a[0],b[0]); r[1]=fmaxf(a[1],b[1]);
  r[2]=fmaxf(a[2],b[2]); r[3]=fmaxf(a[3],b[3]);
  return r;
}

__device__ __forceinline__ void async_copy16(void* lds, const void* g) {
  __builtin_amdgcn_global_load_lds(
      (const __attribute__((address_space(1))) unsigned int*)g,
      (__attribute__((address_space(3))) unsigned int*)lds, 16, 0, 0);
}

// ---------------------------------------------------------------- convert x
__global__ void convert_x_kernel(const float* __restrict__ x,
                                 unsigned short* __restrict__ xb) {
  int i = blockIdx.x * 256 + threadIdx.x;
  const f32x4* xv = reinterpret_cast<const f32x4*>(x);
  f32x4 a = xv[2*i];
  f32x4 b = xv[2*i + 1];
  u16x8 r;
  r[0]=f2bf(a[0]); r[1]=f2bf(a[1]); r[2]=f2bf(a[2]); r[3]=f2bf(a[3]);
  r[4]=f2bf(b[0]); r[5]=f2bf(b[1]); r[6]=f2bf(b[2]); r[7]=f2bf(b[3]);
  reinterpret_cast<u16x8*>(xb)[i] = r;
}

// --------------------------------------- transpose + permute + convert W
__global__ void transpose_w_kernel(const float* __restrict__ W,
                                   unsigned short* __restrict__ Wt) {
  __shared__ float tile[64][65];
  int j0 = blockIdx.x * 64;
  int k0 = blockIdx.y * 64;
  int tid = threadIdx.x;
  int lr = tid >> 6;
  int lc = tid & 63;
  #pragma unroll
  for (int i = 0; i < 16; ++i) {
    int r = i*4 + lr;
    tile[r][lc] = W[(size_t)(k0 + r)*NTOT + j0 + lc];
  }
  __syncthreads();
  #pragma unroll
  for (int i = 0; i < 16; ++i) {
    int jr = i*4 + lr;
    int j  = j0 + jr;
    int oc = (j % 3)*DMODEL + (j / 3);
    Wt[(size_t)oc*KTOT + k0 + lc] = f2bf(tile[lc][jr]);
  }
}

// ---------------------------------------------------------------- QKV GEMM
// R19: T4 counted-vmcnt, 3-buffer staging, prefetch distance 2.
//   iter kt: STAGE(kt+2 -> buf (kt+2)%3) ; compute buf kt%3 ;
//            s_waitcnt vmcnt(4) ; s_barrier     (never vmcnt(0) in steady)
// Ledger: write buf (kt+2)%3 == read buf of iter kt-1, whose ds_reads
// completed before that iter's barrier (MFMA consumption forces lgkm wait);
// reads of buf kt%3 guaranteed landed by the vmcnt(4) at end of kt-1
// (4 gload_lds per thread per tile; newest tile's 4 stay in flight).
// Compute/epilogue identical to R11 (validated): BK=32, T2 swizzle,
// V-epilogue LDS transpose (Ep aliases staging after the final barrier).
#define BM 128
#define BN 128
#define BK2 32
#define NBX (NTOT/BN)    // 24
#define NBY (MTOT/BM)    // 32
#define EPSTRIDE 136     // epilogue LDS row stride (elems): b64/b128 aligned
__launch_bounds__(256)
__global__ void qkv_gemm_kernel(const unsigned short* __restrict__ xb,
                                const unsigned short* __restrict__ wt,
                                const float* __restrict__ bqkv,
                                unsigned short* __restrict__ Qb,
                                unsigned short* __restrict__ Kb,
                                unsigned short* __restrict__ Vt) {
  __shared__ __align__(16) unsigned char gsm[49152];    // 3x(8K A + 8K B)
  unsigned short* As = (unsigned short*)gsm;            // [3][128*32] 24 KB
  unsigned short* Bs = (unsigned short*)(gsm + 24576);  // [3][128*32] 24 KB
  unsigned short* Ep = (unsigned short*)gsm;            // epilogue transpose

  int tid = threadIdx.x;
  int w = tid >> 6, l = tid & 63;
  int m0 = blockIdx.y * BM;
  int n0 = blockIdx.x * BN;
  int ln = l & 15, lg = l >> 4;
  int wm = (w >> 1) * 64;
  int wn = (w & 1) * 64;

  f32x4 acc[4][4];
  const f32x4 zero4 = {0.f, 0.f, 0.f, 0.f};
  #pragma unroll
  for (int i = 0; i < 4; ++i)
    #pragma unroll
    for (int j = 0; j < 4; ++j) acc[i][j] = zero4;

  // stage: linear LDS dest (wave-uniform base + lane*16B), pre-swizzled src
  // 4 global_load_lds per thread per tile (2 A + 2 B)
  #define STAGE2(BUF, KT)                                                     \
  do {                                                                        \
    _Pragma("unroll")                                                         \
    for (int i = 0; i < 2; ++i) {                                             \
      int row  = i*64 + w*16 + (l >> 2);                                      \
      int seg  = (l & 3) ^ ((row >> 1) & 3);                                  \
      async_copy16(gsm + (BUF)*8192 + i*4096 + w*1024,                        \
                   &xb[(size_t)(m0 + row)*KTOT + (KT)*BK2 + seg*8]);          \
      async_copy16(gsm + 24576 + (BUF)*8192 + i*4096 + w*1024,                \
                   &wt[(size_t)(n0 + row)*KTOT + (KT)*BK2 + seg*8]);          \
    }                                                                         \
  } while (0)

  // prologue: tiles 0 and 1 in flight; wait tile 0 (allow tile 1's 4)
  STAGE2(0, 0);
  STAGE2(1, 1);
  asm volatile("s_waitcnt vmcnt(4)" ::: "memory");
  __builtin_amdgcn_s_barrier();
  asm volatile("" ::: "memory");

  int cur = 0, nxt2 = 2;
  for (int kt = 0; kt < KTOT/BK2; ++kt) {
    if (kt < KTOT/BK2 - 2) STAGE2(nxt2, kt + 2);   // stays in flight

    bf16x8 af[4], bfr[4];
    #pragma unroll
    for (int mi = 0; mi < 4; ++mi) {
      int ra = wm + mi*16 + ln;
      af[mi] = *reinterpret_cast<const bf16x8*>(
          &As[cur*4096 + ra*BK2 + ((lg ^ ((ra >> 1) & 3)) << 3)]);
    }
    #pragma unroll
    for (int ni = 0; ni < 4; ++ni) {
      int rb = wn + ni*16 + ln;
      bfr[ni] = *reinterpret_cast<const bf16x8*>(
          &Bs[cur*4096 + rb*BK2 + ((lg ^ ((rb >> 1) & 3)) << 3)]);
    }
    #pragma unroll
    for (int mi = 0; mi < 4; ++mi)
      #pragma unroll
      for (int ni = 0; ni < 4; ++ni)
        acc[mi][ni] = __builtin_amdgcn_mfma_f32_16x16x32_bf16(af[mi], bfr[ni], acc[mi][ni], 0, 0, 0);

    // counted wait: next tile landed; tile kt+2's 4 loads stay in flight
    if (kt < KTOT/BK2 - 2) asm volatile("s_waitcnt vmcnt(4)" ::: "memory");
    else                   asm volatile("s_waitcnt vmcnt(0)" ::: "memory");
    __builtin_amdgcn_s_barrier();
    asm volatile("" ::: "memory");

    cur  = (cur  == 2) ? 0 : cur  + 1;
    nxt2 = (nxt2 == 2) ? 0 : nxt2 + 1;
  }
  #undef STAGE2

  int r4 = lg * 4;
  if (n0 >= 2*DMODEL) {
    // ---- V block (uniform c==2): LDS transpose -> coalesced Vt stores
    // (Ep aliases staging; final loop barrier ordered all reads before this)
    int hd0 = n0 - 2*DMODEL;
    #pragma unroll
    for (int mi = 0; mi < 4; ++mi) {
      #pragma unroll
      for (int ni = 0; ni < 4; ++ni) {
        int col = wn + ni*16 + ln;                 // hd_local
        float bias = bqkv[(hd0 + col)*3 + 2];
        int rb = wm + mi*16 + r4;                  // t_local base (mult of 4)
        ushort4 pk4;
        pk4.x = f2bf(acc[mi][ni][0] + bias);
        pk4.y = f2bf(acc[mi][ni][1] + bias);
        pk4.z = f2bf(acc[mi][ni][2] + bias);
        pk4.w = f2bf(acc[mi][ni][3] + bias);
        *reinterpret_cast<ushort4*>(&Ep[col*EPSTRIDE + rb]) = pk4;
      }
    }
    __syncthreads();
    int n = m0 >> 11, t0 = m0 & 2047;
    #pragma unroll
    for (int pass = 0; pass < 8; ++pass) {
      int hdl = pass*16 + (tid >> 4);
      int seg = tid & 15;
      bf16x8 v = *reinterpret_cast<const bf16x8*>(&Ep[hdl*EPSTRIDE + seg*8]);
      int hd = hd0 + hdl, h = hd >> 6, d = hd & 63;
      *reinterpret_cast<bf16x8*>(
          &Vt[(((size_t)(n*NHEADS + h)*HDIM + d) << 11) + t0 + seg*8]) = v;
    }
  } else {
    // ---- Q/K blocks (c==0/1): 32B-contiguous per 16-lane group
    #pragma unroll
    for (int mi = 0; mi < 4; ++mi) {
      #pragma unroll
      for (int ni = 0; ni < 4; ++ni) {
        int nc = n0 + wn + ni*16 + ln;
        int c  = nc >> 10;
        int hd = nc & 1023;
        int h = hd >> 6, d = hd & 63;
        float bias = bqkv[hd*3 + c];
        float qs = (c == 0) ? QSCALE : 1.0f;   // fold softmax scale into Q
        #pragma unroll
        for (int j = 0; j < 4; ++j) {
          int m = m0 + wm + mi*16 + r4 + j;
          int n = m >> 11, t = m & 2047;
          unsigned short val = f2bf((acc[mi][ni][j] + bias) * qs);
          size_t nh = (size_t)(n*NHEADS + h);
          if (c == 0) Qb[((nh*SEQ + t) << 6) + d] = val;
          else        Kb[((nh*SEQ + t) << 6) + d] = val;
        }
      }
    }
  }
}

// ---------------------------------------------------------------- attention
// R15/R18 attn (best known: ~55.4us) — UNCHANGED. T15 att[2] S-double-
// pipeline + aliasing barrier. Iteration t: STAGE(t+1) | QK(t) MFMA |
// softmax(t-1) VALU | PV(t-1). 3 buffers {t-1, t, t+1}; writer (t+1)%3
// disjoint from both readers; final __syncthreads before obw reuse.
#define PROW    88                  // P row stride, bf16 elems (176 B)
#define POFF    49152               // P regions start (after 3 staging bufs)
#define PBYTES  2816                // 16 rows x 176 B per wave
#define OREGION 4352                // epilogue obuf: 16 x 68 f32 (reuses staging)
__launch_bounds__(512)
__global__ void attn_kernel(const unsigned short* __restrict__ Qb,
                            const unsigned short* __restrict__ Kb,
                            const unsigned short* __restrict__ Vt,
                            float* __restrict__ out) {
  __shared__ __align__(16) unsigned char smem[POFF + 8*PBYTES]; // 71680 B
  int tid = threadIdx.x;
  int w = tid >> 6, l = tid & 63;
  int ln = l & 15, lg = l >> 4;

  unsigned short* Pw  = (unsigned short*)(smem + POFF + w * PBYTES);
  float*          obw = (float*)         (smem + w * OREGION); // post-loop only

  // XCD clustering: 512 blocks, 8 XCDs -> each XCD owns 4 heads
  int fid  = blockIdx.x;
  int xcd  = fid & 7, idx = fid >> 3;       // idx 0..63
  int bh   = xcd * 4 + (idx >> 4);          // 0..31
  int qblk = idx & 15;                      // 0..15 (128 q-rows each)
  int q0   = qblk * 128 + w * 16;

  const unsigned short* Qh = Qb + (size_t)bh * SEQ * HDIM;
  const unsigned short* Kh = Kb + (size_t)bh * SEQ * HDIM;
  const unsigned short* Vh = Vt + (size_t)bh * HDIM * SEQ;

  // staging mapping: 512 threads cover one 64x64 bf16 tile in ONE call
  int srow = w*8 + (l >> 3);      // row 0..63
  int sseg = (l & 7) ^ (srow & 7);// inverse-swizzled 16B segment

  // Q B-fragments (col = q = ln), d-windows dw=0,1
  bf16x8 qf[2];
  #pragma unroll
  for (int dw = 0; dw < 2; ++dw)
    qf[dw] = *reinterpret_cast<const bf16x8*>(&Qh[(size_t)(q0 + ln)*HDIM + dw*32 + lg*8]);

  const f32x4 zero4 = {0.f, 0.f, 0.f, 0.f};
  f32x4 o[4];
  #pragma unroll
  for (int db = 0; db < 4; ++db) o[db] = zero4;
  f32x4 psum4 = zero4;
  float mrow = -INFINITY;
  f32x4 sA[4], sB[4];

  int xorE = (ln & 7) << 3;        // element-index XOR for swizzled ds_read
  int coff0 = (((     lg*8) ^ xorE)) * 2;   // d-window 0 column bytes
  int coff1 = (((32 + lg*8) ^ xorE)) * 2;   // d-window 1 column bytes
  int rbyte = ln * 128;                     // fragment row base bytes
  const unsigned char* kv0 = smem + rbyte + coff0;
  const unsigned char* kv1 = smem + rbyte + coff1;

  // STAGE one 64-key tile into buffer BUF: K[key][d] + V[d][key]
  #define STAGE(BUF, KEY0)                                                    \
  do {                                                                        \
    async_copy16(smem + (BUF)*16384 + w*1024,                                 \
                 &Kh[(size_t)((KEY0) + srow)*HDIM + sseg*8]);                 \
    async_copy16(smem + (BUF)*16384 + 8192 + w*1024,                          \
                 &Vh[(size_t)srow*SEQ + (KEY0) + sseg*8]);                    \
  } while (0)

  // QK^T for tile in buffer CUR -> SCUR (pure MFMA + ds_read stream)
  #define QKT(CUR, SCUR)                                                      \
  do {                                                                        \
    _Pragma("unroll")                                                         \
    for (int kb = 0; kb < 4; ++kb) {                                          \
      bf16x8 k0 = *reinterpret_cast<const bf16x8*>(kv0 + (CUR)*16384 + kb*2048);\
      bf16x8 k1 = *reinterpret_cast<const bf16x8*>(kv1 + (CUR)*16384 + kb*2048);\
      f32x4 t0 = __builtin_amdgcn_mfma_f32_16x16x32_bf16(k0, qf[0], zero4, 0, 0, 0);\
      SCUR[kb] = __builtin_amdgcn_mfma_f32_16x16x32_bf16(k1, qf[1], t0,    0, 0, 0);\
    }                                                                         \
  } while (0)

  // softmax on SPREV + PV with V from buffer PRV (VALU stream + PV MFMAs)
  #define SMPV(SPREV, PRV)                                                    \
  do {                                                                        \
    f32x4 m4 = vmax4(vmax4(SPREV[0], SPREV[1]), vmax4(SPREV[2], SPREV[3]));   \
    float localmax = fmaxf(fmaxf(fmaxf(m4[0], m4[1]), m4[2]), m4[3]);         \
    if (!__all(localmax <= mrow + 8.f)) {                                     \
      float pm = localmax;                                                    \
      pm = fmaxf(pm, __shfl_xor(pm, 16));                                     \
      pm = fmaxf(pm, __shfl_xor(pm, 32));                                     \
      float mn  = fmaxf(mrow, pm);                                            \
      float scl = __builtin_amdgcn_exp2f(mrow - mn);                          \
      mrow = mn;                                                              \
      psum4 *= scl;                                                           \
      _Pragma("unroll")                                                       \
      for (int db = 0; db < 4; ++db)                                          \
        _Pragma("unroll")                                                     \
        for (int r = 0; r < 4; ++r) o[db][r] *= scl;                          \
    }                                                                         \
    _Pragma("unroll")                                                         \
    for (int kb = 0; kb < 4; ++kb) {                                          \
      _Pragma("unroll")                                                       \
      for (int r = 0; r < 4; ++r)                                             \
        SPREV[kb][r] = __builtin_amdgcn_exp2f(SPREV[kb][r] - mrow);           \
      psum4 += SPREV[kb];                                                     \
    }                                                                         \
    _Pragma("unroll")                                                         \
    for (int kb = 0; kb < 4; ++kb) {                                          \
      uint2 pk;                                                               \
      asm("v_cvt_pk_bf16_f32 %0, %1, %2" : "=v"(pk.x) : "v"(SPREV[kb][0]), "v"(SPREV[kb][1]));\
      asm("v_cvt_pk_bf16_f32 %0, %1, %2" : "=v"(pk.y) : "v"(SPREV[kb][2]), "v"(SPREV[kb][3]));\
      *reinterpret_cast<uint2*>(&Pw[ln*PROW + kb*16 + 4*lg]) = pk;            \
    }                                                                         \
    _Pragma("unroll")                                                         \
    for (int kw = 0; kw < 2; ++kw) {                                          \
      bf16x8 pb = *reinterpret_cast<const bf16x8*>(&Pw[ln*PROW + kw*32 + lg*8]);\
      const unsigned char* vb = (kw == 0) ? kv0 : kv1;                        \
      __builtin_amdgcn_s_setprio(1);                                          \
      _Pragma("unroll")                                                       \
      for (int db = 0; db < 4; ++db) {                                        \
        bf16x8 vfr = *reinterpret_cast<const bf16x8*>(                        \
            vb + (PRV)*16384 + 8192 + db*2048);                               \
        o[db] = __builtin_amdgcn_mfma_f32_16x16x32_bf16(vfr, pb, o[db], 0, 0, 0);\
      }                                                                       \
      __builtin_amdgcn_s_setprio(0);                                          \
    }                                                                         \
  } while (0)

  #define ENDTILE                                                             \
  do {                                                                        \
    asm volatile("s_waitcnt vmcnt(0)" ::: "memory");                          \
    __builtin_amdgcn_s_barrier();                                             \
    asm volatile("" ::: "memory");                                            \
  } while (0)

  // FULL iteration t: stage(t+1), QK(t)->SCUR, softmax+PV(t-1) from SPREV
  #define FULL(KV, CUR, PRV, NXT, SPREV, SCUR)                                \
  do {                                                                        \
    STAGE(NXT, ((KV) + 1) * 64);                                              \
    QKT(CUR, SCUR);                                                           \
    SMPV(SPREV, PRV);                                                         \
    ENDTILE;                                                                  \
  } while (0)

  // ---- prologue: tile 0 staged+computed, tile 1 staged
  STAGE(0, 0);
  ENDTILE;                 // buffer 0 ready
  STAGE(1, 64);
  QKT(0, sA);              // S(0) -> sA
  ENDTILE;                 // buffer 1 ready

  // ---- main loop t = 1..30 (6-unrolled: buffer period 3 x S period 2)
  for (int t = 1; t < 31; t += 6) {
    FULL(t + 0, 1, 0, 2, sA, sB);
    FULL(t + 1, 2, 1, 0, sB, sA);
    FULL(t + 2, 0, 2, 1, sA, sB);
    FULL(t + 3, 1, 0, 2, sB, sA);
    FULL(t + 4, 2, 1, 0, sA, sB);
    FULL(t + 5, 0, 2, 1, sB, sA);
  }

  // ---- t = 31: no stage; QK(31)->sB (buf 1), softmax+PV(30) (V buf 0)
  QKT(1, sB);
  SMPV(sA, 0);
  ENDTILE;
  // ---- final: softmax+PV(31) (V buf 1)
  SMPV(sB, 1);

  // obw aliases staging buffers 0/1 — all waves must finish their
  // V reads (buffers 0 AND 1) before any wave reuses the LDS as obw.
  __syncthreads();

  #undef FULL
  #undef ENDTILE
  #undef SMPV
  #undef QKT
  #undef STAGE

  // ---- post-loop: row-sum reduce (once), normalize, transpose, store
  float ls = (psum4[0] + psum4[1]) + (psum4[2] + psum4[3]);
  ls += __shfl_xor(ls, 16);
  ls += __shfl_xor(ls, 32);
  float inv = 1.f / ls;

  #pragma unroll
  for (int db = 0; db < 4; ++db)
    #pragma unroll
    for (int r = 0; r < 4; ++r)
      obw[ln*68 + db*16 + 4*lg + r] = o[db][r] * inv;
  asm volatile("s_waitcnt lgkmcnt(0)" ::: "memory");
  int n = bh >> 4, h = bh & 15;
  #pragma unroll
  for (int p = 0; p < 4; ++p) {
    int q = p*4 + lg;
    f32x4 vv = *reinterpret_cast<const f32x4*>(&obw[q*68 + ln*4]);
    *reinterpret_cast<f32x4*>(
        &out[((size_t)(n*SEQ + q0 + q))*DMODEL + h*HDIM + ln*4]) = vv;
  }
}

// ---------------------------------------------------------------- launcher
extern "C" void kernel_launch(void* const* d_in, const int* in_sizes, int n_in,
                              void* d_out, int out_size, void* d_ws, size_t ws_size,
                              hipStream_t stream) {
  const float* x    = (const float*)d_in[0];
  // d_in[1] = mask: constant shift along query axis inside softmax -> no-op
  const float* Wq   = (const float*)d_in[2];
  const float* bq   = (const float*)d_in[3];
  float* out = (float*)d_out;

  unsigned short* xb = (unsigned short*)d_ws;                    // [4096][1024]
  unsigned short* wt = xb + (size_t)MTOT*KTOT;                   // [3072][1024]
  unsigned short* Qb = wt + (size_t)NTOT*KTOT;                   // [32][2048][64]
  unsigned short* Kb = Qb + (size_t)NB*NHEADS*SEQ*HDIM;          // [32][2048][64]
  unsigned short* Vt = Kb + (size_t)NB*NHEADS*SEQ*HDIM;          // [32][64][2048]

  convert_x_kernel<<<(MTOT*KTOT/8)/256, 256, 0, stream>>>(x, xb);
  transpose_w_kernel<<<dim3(NTOT/64, KTOT/64), 256, 0, stream>>>(Wq, wt);
  qkv_gemm_kernel<<<dim3(NBX, NBY), 256, 0, stream>>>(xb, wt, bq, Qb, Kb, Vt);
  attn_kernel<<<512, 512, 0, stream>>>(Qb, Kb, Vt, out);
}

// Round 20
// 98.042 us; speedup vs baseline: 2.1368x; 1.0192x over previous
//
#include <hip/hip_runtime.h>
#include <hip/hip_bf16.h>
#include <stdint.h>

// Sizes (fixed for this problem)
#define NHEADS 16
#define HDIM   64
#define DMODEL 1024
#define SEQ    2048
#define NB     2
#define MTOT   (NB*SEQ)     // 4096 rows of x
#define NTOT   (3*DMODEL)   // 3072 qkv cols
#define KTOT   DMODEL       // 1024

// fold (1/8)*log2(e) into Q so softmax runs in exp2 domain
#define QSCALE 0.18033688011112042f

typedef __attribute__((ext_vector_type(8)))  short          bf16x8;
typedef __attribute__((ext_vector_type(4)))  float          f32x4;
typedef __attribute__((ext_vector_type(8)))  unsigned short u16x8;

__device__ __forceinline__ unsigned short f2bf(float f) {
  unsigned u = __builtin_bit_cast(unsigned, f);
  u += 0x7fffu + ((u >> 16) & 1u);          // round-to-nearest-even
  return (unsigned short)(u >> 16);
}

__device__ __forceinline__ f32x4 vmax4(f32x4 a, f32x4 b) {
  f32x4 r;
  r[0]=fmaxf(a[0],b[0]); r[1]=fmaxf(a[1],b[1]);
  r[2]=fmaxf(a[2],b[2]); r[3]=fmaxf(a[3],b[3]);
  return r;
}

__device__ __forceinline__ void async_copy16(void* lds, const void* g) {
  __builtin_amdgcn_global_load_lds(
      (const __attribute__((address_space(1))) unsigned int*)g,
      (__attribute__((address_space(3))) unsigned int*)lds, 16, 0, 0);
}

// ------------------------------------------------ fused prep (R20)
// convert_x (blocks 0..2047) and transpose_w (blocks 2048..2815) are
// independent; fusing them into ONE launch lets them co-run (both are
// HBM-floor bound: 24MB + 18MB) and removes a launch gap. Branch is
// block-uniform; bodies are byte-identical to the R19 kernels.
#define CVT_BLOCKS 2048   // MTOT*KTOT/8/256
#define TW_BX 48          // NTOT/64
__launch_bounds__(256)
__global__ void prep_kernel(const float* __restrict__ x,
                            const float* __restrict__ W,
                            unsigned short* __restrict__ xb,
                            unsigned short* __restrict__ Wt) {
  __shared__ float tile[64][65];
  int b = blockIdx.x;
  if (b < CVT_BLOCKS) {
    // ---- convert x -> bf16
    int i = b * 256 + threadIdx.x;
    const f32x4* xv = reinterpret_cast<const f32x4*>(x);
    f32x4 a = xv[2*i];
    f32x4 c = xv[2*i + 1];
    u16x8 r;
    r[0]=f2bf(a[0]); r[1]=f2bf(a[1]); r[2]=f2bf(a[2]); r[3]=f2bf(a[3]);
    r[4]=f2bf(c[0]); r[5]=f2bf(c[1]); r[6]=f2bf(c[2]); r[7]=f2bf(c[3]);
    reinterpret_cast<u16x8*>(xb)[i] = r;
  } else {
    // ---- transpose + permute + convert W
    int id = b - CVT_BLOCKS;
    int j0 = (id % TW_BX) * 64;
    int k0 = (id / TW_BX) * 64;
    int tid = threadIdx.x;
    int lr = tid >> 6;
    int lc = tid & 63;
    #pragma unroll
    for (int i = 0; i < 16; ++i) {
      int r = i*4 + lr;
      tile[r][lc] = W[(size_t)(k0 + r)*NTOT + j0 + lc];
    }
    __syncthreads();
    #pragma unroll
    for (int i = 0; i < 16; ++i) {
      int jr = i*4 + lr;
      int j  = j0 + jr;
      int oc = (j % 3)*DMODEL + (j / 3);
      Wt[(size_t)oc*KTOT + k0 + lc] = f2bf(tile[lc][jr]);
    }
  }
}

// ---------------------------------------------------------------- QKV GEMM
// R19 (kept): T4 counted-vmcnt, 3-buffer staging, prefetch distance 2.
//   iter kt: STAGE(kt+2 -> buf (kt+2)%3) ; compute buf kt%3 ;
//            s_waitcnt vmcnt(4) ; s_barrier     (never vmcnt(0) in steady)
// Compute/epilogue identical to R11 (validated): BK=32, T2 swizzle,
// V-epilogue LDS transpose (Ep aliases staging after the final barrier).
#define BM 128
#define BN 128
#define BK2 32
#define NBX (NTOT/BN)    // 24
#define NBY (MTOT/BM)    // 32
#define EPSTRIDE 136     // epilogue LDS row stride (elems): b64/b128 aligned
__launch_bounds__(256)
__global__ void qkv_gemm_kernel(const unsigned short* __restrict__ xb,
                                const unsigned short* __restrict__ wt,
                                const float* __restrict__ bqkv,
                                unsigned short* __restrict__ Qb,
                                unsigned short* __restrict__ Kb,
                                unsigned short* __restrict__ Vt) {
  __shared__ __align__(16) unsigned char gsm[49152];    // 3x(8K A + 8K B)
  unsigned short* As = (unsigned short*)gsm;            // [3][128*32] 24 KB
  unsigned short* Bs = (unsigned short*)(gsm + 24576);  // [3][128*32] 24 KB
  unsigned short* Ep = (unsigned short*)gsm;            // epilogue transpose

  int tid = threadIdx.x;
  int w = tid >> 6, l = tid & 63;
  int m0 = blockIdx.y * BM;
  int n0 = blockIdx.x * BN;
  int ln = l & 15, lg = l >> 4;
  int wm = (w >> 1) * 64;
  int wn = (w & 1) * 64;

  f32x4 acc[4][4];
  const f32x4 zero4 = {0.f, 0.f, 0.f, 0.f};
  #pragma unroll
  for (int i = 0; i < 4; ++i)
    #pragma unroll
    for (int j = 0; j < 4; ++j) acc[i][j] = zero4;

  // stage: linear LDS dest (wave-uniform base + lane*16B), pre-swizzled src
  // 4 global_load_lds per thread per tile (2 A + 2 B)
  #define STAGE2(BUF, KT)                                                     \
  do {                                                                        \
    _Pragma("unroll")                                                         \
    for (int i = 0; i < 2; ++i) {                                             \
      int row  = i*64 + w*16 + (l >> 2);                                      \
      int seg  = (l & 3) ^ ((row >> 1) & 3);                                  \
      async_copy16(gsm + (BUF)*8192 + i*4096 + w*1024,                        \
                   &xb[(size_t)(m0 + row)*KTOT + (KT)*BK2 + seg*8]);          \
      async_copy16(gsm + 24576 + (BUF)*8192 + i*4096 + w*1024,                \
                   &wt[(size_t)(n0 + row)*KTOT + (KT)*BK2 + seg*8]);          \
    }                                                                         \
  } while (0)

  // prologue: tiles 0 and 1 in flight; wait tile 0 (allow tile 1's 4)
  STAGE2(0, 0);
  STAGE2(1, 1);
  asm volatile("s_waitcnt vmcnt(4)" ::: "memory");
  __builtin_amdgcn_s_barrier();
  asm volatile("" ::: "memory");

  int cur = 0, nxt2 = 2;
  for (int kt = 0; kt < KTOT/BK2; ++kt) {
    if (kt < KTOT/BK2 - 2) STAGE2(nxt2, kt + 2);   // stays in flight

    bf16x8 af[4], bfr[4];
    #pragma unroll
    for (int mi = 0; mi < 4; ++mi) {
      int ra = wm + mi*16 + ln;
      af[mi] = *reinterpret_cast<const bf16x8*>(
          &As[cur*4096 + ra*BK2 + ((lg ^ ((ra >> 1) & 3)) << 3)]);
    }
    #pragma unroll
    for (int ni = 0; ni < 4; ++ni) {
      int rb = wn + ni*16 + ln;
      bfr[ni] = *reinterpret_cast<const bf16x8*>(
          &Bs[cur*4096 + rb*BK2 + ((lg ^ ((rb >> 1) & 3)) << 3)]);
    }
    #pragma unroll
    for (int mi = 0; mi < 4; ++mi)
      #pragma unroll
      for (int ni = 0; ni < 4; ++ni)
        acc[mi][ni] = __builtin_amdgcn_mfma_f32_16x16x32_bf16(af[mi], bfr[ni], acc[mi][ni], 0, 0, 0);

    // counted wait: next tile landed; tile kt+2's 4 loads stay in flight
    if (kt < KTOT/BK2 - 2) asm volatile("s_waitcnt vmcnt(4)" ::: "memory");
    else                   asm volatile("s_waitcnt vmcnt(0)" ::: "memory");
    __builtin_amdgcn_s_barrier();
    asm volatile("" ::: "memory");

    cur  = (cur  == 2) ? 0 : cur  + 1;
    nxt2 = (nxt2 == 2) ? 0 : nxt2 + 1;
  }
  #undef STAGE2

  int r4 = lg * 4;
  if (n0 >= 2*DMODEL) {
    // ---- V block (uniform c==2): LDS transpose -> coalesced Vt stores
    int hd0 = n0 - 2*DMODEL;
    #pragma unroll
    for (int mi = 0; mi < 4; ++mi) {
      #pragma unroll
      for (int ni = 0; ni < 4; ++ni) {
        int col = wn + ni*16 + ln;                 // hd_local
        float bias = bqkv[(hd0 + col)*3 + 2];
        int rb = wm + mi*16 + r4;                  // t_local base (mult of 4)
        ushort4 pk4;
        pk4.x = f2bf(acc[mi][ni][0] + bias);
        pk4.y = f2bf(acc[mi][ni][1] + bias);
        pk4.z = f2bf(acc[mi][ni][2] + bias);
        pk4.w = f2bf(acc[mi][ni][3] + bias);
        *reinterpret_cast<ushort4*>(&Ep[col*EPSTRIDE + rb]) = pk4;
      }
    }
    __syncthreads();
    int n = m0 >> 11, t0 = m0 & 2047;
    #pragma unroll
    for (int pass = 0; pass < 8; ++pass) {
      int hdl = pass*16 + (tid >> 4);
      int seg = tid & 15;
      bf16x8 v = *reinterpret_cast<const bf16x8*>(&Ep[hdl*EPSTRIDE + seg*8]);
      int hd = hd0 + hdl, h = hd >> 6, d = hd & 63;
      *reinterpret_cast<bf16x8*>(
          &Vt[(((size_t)(n*NHEADS + h)*HDIM + d) << 11) + t0 + seg*8]) = v;
    }
  } else {
    // ---- Q/K blocks (c==0/1): 32B-contiguous per 16-lane group
    #pragma unroll
    for (int mi = 0; mi < 4; ++mi) {
      #pragma unroll
      for (int ni = 0; ni < 4; ++ni) {
        int nc = n0 + wn + ni*16 + ln;
        int c  = nc >> 10;
        int hd = nc & 1023;
        int h = hd >> 6, d = hd & 63;
        float bias = bqkv[hd*3 + c];
        float qs = (c == 0) ? QSCALE : 1.0f;   // fold softmax scale into Q
        #pragma unroll
        for (int j = 0; j < 4; ++j) {
          int m = m0 + wm + mi*16 + r4 + j;
          int n = m >> 11, t = m & 2047;
          unsigned short val = f2bf((acc[mi][ni][j] + bias) * qs);
          size_t nh = (size_t)(n*NHEADS + h);
          if (c == 0) Qb[((nh*SEQ + t) << 6) + d] = val;
          else        Kb[((nh*SEQ + t) << 6) + d] = val;
        }
      }
    }
  }
}

// ---------------------------------------------------------------- attention
// R15/R18/R19 attn (best known: ~55.5us) — UNCHANGED. T15 att[2] S-double-
// pipeline + aliasing barrier. Iteration t: STAGE(t+1) | QK(t) MFMA |
// softmax(t-1) VALU | PV(t-1). 3 buffers {t-1, t, t+1}; writer (t+1)%3
// disjoint from both readers; final __syncthreads before obw reuse.
#define PROW    88                  // P row stride, bf16 elems (176 B)
#define POFF    49152               // P regions start (after 3 staging bufs)
#define PBYTES  2816                // 16 rows x 176 B per wave
#define OREGION 4352                // epilogue obuf: 16 x 68 f32 (reuses staging)
__launch_bounds__(512)
__global__ void attn_kernel(const unsigned short* __restrict__ Qb,
                            const unsigned short* __restrict__ Kb,
                            const unsigned short* __restrict__ Vt,
                            float* __restrict__ out) {
  __shared__ __align__(16) unsigned char smem[POFF + 8*PBYTES]; // 71680 B
  int tid = threadIdx.x;
  int w = tid >> 6, l = tid & 63;
  int ln = l & 15, lg = l >> 4;

  unsigned short* Pw  = (unsigned short*)(smem + POFF + w * PBYTES);
  float*          obw = (float*)         (smem + w * OREGION); // post-loop only

  // XCD clustering: 512 blocks, 8 XCDs -> each XCD owns 4 heads
  int fid  = blockIdx.x;
  int xcd  = fid & 7, idx = fid >> 3;       // idx 0..63
  int bh   = xcd * 4 + (idx >> 4);          // 0..31
  int qblk = idx & 15;                      // 0..15 (128 q-rows each)
  int q0   = qblk * 128 + w * 16;

  const unsigned short* Qh = Qb + (size_t)bh * SEQ * HDIM;
  const unsigned short* Kh = Kb + (size_t)bh * SEQ * HDIM;
  const unsigned short* Vh = Vt + (size_t)bh * HDIM * SEQ;

  // staging mapping: 512 threads cover one 64x64 bf16 tile in ONE call
  int srow = w*8 + (l >> 3);      // row 0..63
  int sseg = (l & 7) ^ (srow & 7);// inverse-swizzled 16B segment

  // Q B-fragments (col = q = ln), d-windows dw=0,1
  bf16x8 qf[2];
  #pragma unroll
  for (int dw = 0; dw < 2; ++dw)
    qf[dw] = *reinterpret_cast<const bf16x8*>(&Qh[(size_t)(q0 + ln)*HDIM + dw*32 + lg*8]);

  const f32x4 zero4 = {0.f, 0.f, 0.f, 0.f};
  f32x4 o[4];
  #pragma unroll
  for (int db = 0; db < 4; ++db) o[db] = zero4;
  f32x4 psum4 = zero4;
  float mrow = -INFINITY;
  f32x4 sA[4], sB[4];

  int xorE = (ln & 7) << 3;        // element-index XOR for swizzled ds_read
  int coff0 = (((     lg*8) ^ xorE)) * 2;   // d-window 0 column bytes
  int coff1 = (((32 + lg*8) ^ xorE)) * 2;   // d-window 1 column bytes
  int rbyte = ln * 128;                     // fragment row base bytes
  const unsigned char* kv0 = smem + rbyte + coff0;
  const unsigned char* kv1 = smem + rbyte + coff1;

  // STAGE one 64-key tile into buffer BUF: K[key][d] + V[d][key]
  #define STAGE(BUF, KEY0)                                                    \
  do {                                                                        \
    async_copy16(smem + (BUF)*16384 + w*1024,                                 \
                 &Kh[(size_t)((KEY0) + srow)*HDIM + sseg*8]);                 \
    async_copy16(smem + (BUF)*16384 + 8192 + w*1024,                          \
                 &Vh[(size_t)srow*SEQ + (KEY0) + sseg*8]);                    \
  } while (0)

  // QK^T for tile in buffer CUR -> SCUR (pure MFMA + ds_read stream)
  #define QKT(CUR, SCUR)                                                      \
  do {                                                                        \
    _Pragma("unroll")                                                         \
    for (int kb = 0; kb < 4; ++kb) {                                          \
      bf16x8 k0 = *reinterpret_cast<const bf16x8*>(kv0 + (CUR)*16384 + kb*2048);\
      bf16x8 k1 = *reinterpret_cast<const bf16x8*>(kv1 + (CUR)*16384 + kb*2048);\
      f32x4 t0 = __builtin_amdgcn_mfma_f32_16x16x32_bf16(k0, qf[0], zero4, 0, 0, 0);\
      SCUR[kb] = __builtin_amdgcn_mfma_f32_16x16x32_bf16(k1, qf[1], t0,    0, 0, 0);\
    }                                                                         \
  } while (0)

  // softmax on SPREV + PV with V from buffer PRV (VALU stream + PV MFMAs)
  #define SMPV(SPREV, PRV)                                                    \
  do {                                                                        \
    f32x4 m4 = vmax4(vmax4(SPREV[0], SPREV[1]), vmax4(SPREV[2], SPREV[3]));   \
    float localmax = fmaxf(fmaxf(fmaxf(m4[0], m4[1]), m4[2]), m4[3]);         \
    if (!__all(localmax <= mrow + 8.f)) {                                     \
      float pm = localmax;                                                    \
      pm = fmaxf(pm, __shfl_xor(pm, 16));                                     \
      pm = fmaxf(pm, __shfl_xor(pm, 32));                                     \
      float mn  = fmaxf(mrow, pm);                                            \
      float scl = __builtin_amdgcn_exp2f(mrow - mn);                          \
      mrow = mn;                                                              \
      psum4 *= scl;                                                           \
      _Pragma("unroll")                                                       \
      for (int db = 0; db < 4; ++db)                                          \
        _Pragma("unroll")                                                     \
        for (int r = 0; r < 4; ++r) o[db][r] *= scl;                          \
    }                                                                         \
    _Pragma("unroll")                                                         \
    for (int kb = 0; kb < 4; ++kb) {                                          \
      _Pragma("unroll")                                                       \
      for (int r = 0; r < 4; ++r)                                             \
        SPREV[kb][r] = __builtin_amdgcn_exp2f(SPREV[kb][r] - mrow);           \
      psum4 += SPREV[kb];                                                     \
    }                                                                         \
    _Pragma("unroll")                                                         \
    for (int kb = 0; kb < 4; ++kb) {                                          \
      uint2 pk;                                                               \
      asm("v_cvt_pk_bf16_f32 %0, %1, %2" : "=v"(pk.x) : "v"(SPREV[kb][0]), "v"(SPREV[kb][1]));\
      asm("v_cvt_pk_bf16_f32 %0, %1, %2" : "=v"(pk.y) : "v"(SPREV[kb][2]), "v"(SPREV[kb][3]));\
      *reinterpret_cast<uint2*>(&Pw[ln*PROW + kb*16 + 4*lg]) = pk;            \
    }                                                                         \
    _Pragma("unroll")                                                         \
    for (int kw = 0; kw < 2; ++kw) {                                          \
      bf16x8 pb = *reinterpret_cast<const bf16x8*>(&Pw[ln*PROW + kw*32 + lg*8]);\
      const unsigned char* vb = (kw == 0) ? kv0 : kv1;                        \
      __builtin_amdgcn_s_setprio(1);                                          \
      _Pragma("unroll")                                                       \
      for (int db = 0; db < 4; ++db) {                                        \
        bf16x8 vfr = *reinterpret_cast<const bf16x8*>(                        \
            vb + (PRV)*16384 + 8192 + db*2048);                               \
        o[db] = __builtin_amdgcn_mfma_f32_16x16x32_bf16(vfr, pb, o[db], 0, 0, 0);\
      }                                                                       \
      __builtin_amdgcn_s_setprio(0);                                          \
    }                                                                         \
  } while (0)

  #define ENDTILE                                                             \
  do {                                                                        \
    asm volatile("s_waitcnt vmcnt(0)" ::: "memory");                          \
    __builtin_amdgcn_s_barrier();                                             \
    asm volatile("" ::: "memory");                                            \
  } while (0)

  // FULL iteration t: stage(t+1), QK(t)->SCUR, softmax+PV(t-1) from SPREV
  #define FULL(KV, CUR, PRV, NXT, SPREV, SCUR)                                \
  do {                                                                        \
    STAGE(NXT, ((KV) + 1) * 64);                                              \
    QKT(CUR, SCUR);                                                           \
    SMPV(SPREV, PRV);                                                         \
    ENDTILE;                                                                  \
  } while (0)

  // ---- prologue: tile 0 staged+computed, tile 1 staged
  STAGE(0, 0);
  ENDTILE;                 // buffer 0 ready
  STAGE(1, 64);
  QKT(0, sA);              // S(0) -> sA
  ENDTILE;                 // buffer 1 ready

  // ---- main loop t = 1..30 (6-unrolled: buffer period 3 x S period 2)
  for (int t = 1; t < 31; t += 6) {
    FULL(t + 0, 1, 0, 2, sA, sB);
    FULL(t + 1, 2, 1, 0, sB, sA);
    FULL(t + 2, 0, 2, 1, sA, sB);
    FULL(t + 3, 1, 0, 2, sB, sA);
    FULL(t + 4, 2, 1, 0, sA, sB);
    FULL(t + 5, 0, 2, 1, sB, sA);
  }

  // ---- t = 31: no stage; QK(31)->sB (buf 1), softmax+PV(30) (V buf 0)
  QKT(1, sB);
  SMPV(sA, 0);
  ENDTILE;
  // ---- final: softmax+PV(31) (V buf 1)
  SMPV(sB, 1);

  // obw aliases staging buffers 0/1 — all waves must finish their
  // V reads (buffers 0 AND 1) before any wave reuses the LDS as obw.
  __syncthreads();

  #undef FULL
  #undef ENDTILE
  #undef SMPV
  #undef QKT
  #undef STAGE

  // ---- post-loop: row-sum reduce (once), normalize, transpose, store
  float ls = (psum4[0] + psum4[1]) + (psum4[2] + psum4[3]);
  ls += __shfl_xor(ls, 16);
  ls += __shfl_xor(ls, 32);
  float inv = 1.f / ls;

  #pragma unroll
  for (int db = 0; db < 4; ++db)
    #pragma unroll
    for (int r = 0; r < 4; ++r)
      obw[ln*68 + db*16 + 4*lg + r] = o[db][r] * inv;
  asm volatile("s_waitcnt lgkmcnt(0)" ::: "memory");
  int n = bh >> 4, h = bh & 15;
  #pragma unroll
  for (int p = 0; p < 4; ++p) {
    int q = p*4 + lg;
    f32x4 vv = *reinterpret_cast<const f32x4*>(&obw[q*68 + ln*4]);
    *reinterpret_cast<f32x4*>(
        &out[((size_t)(n*SEQ + q0 + q))*DMODEL + h*HDIM + ln*4]) = vv;
  }
}

// ---------------------------------------------------------------- launcher
extern "C" void kernel_launch(void* const* d_in, const int* in_sizes, int n_in,
                              void* d_out, int out_size, void* d_ws, size_t ws_size,
                              hipStream_t stream) {
  const float* x    = (const float*)d_in[0];
  // d_in[1] = mask: constant shift along query axis inside softmax -> no-op
  const float* Wq   = (const float*)d_in[2];
  const float* bq   = (const float*)d_in[3];
  float* out = (float*)d_out;

  unsigned short* xb = (unsigned short*)d_ws;                    // [4096][1024]
  unsigned short* wt = xb + (size_t)MTOT*KTOT;                   // [3072][1024]
  unsigned short* Qb = wt + (size_t)NTOT*KTOT;                   // [32][2048][64]
  unsigned short* Kb = Qb + (size_t)NB*NHEADS*SEQ*HDIM;          // [32][2048][64]
  unsigned short* Vt = Kb + (size_t)NB*NHEADS*SEQ*HDIM;          // [32][64][2048]

  prep_kernel<<<CVT_BLOCKS + TW_BX*(KTOT/64), 256, 0, stream>>>(x, Wq, xb, wt);
  qkv_gemm_kernel<<<dim3(NBX, NBY), 256, 0, stream>>>(xb, wt, bq, Qb, Kb, Vt);
  attn_kernel<<<512, 512, 0, stream>>>(Qb, Kb, Vt, out);
}